// Round 9
// baseline (1329.042 us; speedup 1.0000x reference)
//
#include <hip/hip_runtime.h>
#include <hip/hip_bf16.h>
#include <math.h>

// ---------------- constants ----------------
constexpr int B_  = 128;
constexpr int S_  = 128;
constexpr int FIN_= 16;
constexpr int D_  = 128;
constexpr int H_  = 8;
constexpr int F_  = 512;
constexpr float EPSF = 1e-5f;
constexpr float BN_SCALE_F = 0.99999500003749967f;  // 1/sqrt(1+1e-5)
constexpr float PI_F  = 3.14159265358979323846f;
constexpr float TWO_PI_F = 6.283185307179586477f;
constexpr float INV_TWO_PI_F = 0.15915494309189533577f;

using short8v = __attribute__((ext_vector_type(8))) short;
using float4v = __attribute__((ext_vector_type(4))) float;

__device__ __forceinline__ float gelu_f(float x) {
    return 0.5f * x * (1.0f + erff(x * 0.70710678118654752f));
}

// Abramowitz-Stegun 7.1.26 erf (|abs err| <= 1.5e-7); consumers bf16-quantize.
__device__ __forceinline__ float gelu_fast(float x) {
    float z = fabsf(x) * 0.70710678118654752f;
    float t = __builtin_amdgcn_rcpf(1.0f + 0.3275911f * z);
    float poly = t*(0.254829592f + t*(-0.284496736f + t*(1.421413741f + t*(-1.453152027f + t*1.061405429f))));
    float e = 1.0f - poly * __expf(-z*z);
    float s = (x >= 0.f) ? e : -e;
    return 0.5f * x * (1.0f + s);
}

__device__ __forceinline__ short f2b(float f) {
    union { __hip_bfloat16 h; short s; } u;
    u.h = __float2bfloat16(f);
    return u.s;
}

// ---------------- prep: pt/rap/phi + key-padding mask ----------------
__global__ __launch_bounds__(256) void prep_kernel(
    const float* __restrict__ x, const float* __restrict__ p4,
    float* __restrict__ prep, float* __restrict__ kpm)
{
    int idx = blockIdx.x * 256 + threadIdx.x;
    float px = p4[(size_t)idx*4 + 0];
    float py = p4[(size_t)idx*4 + 1];
    float pz = p4[(size_t)idx*4 + 2];
    float e  = p4[(size_t)idx*4 + 3];
    float pt = sqrtf(px*px + py*py);
    float den = fmaxf(e - pz, 1e-20f);
    float rap = 0.5f * log1pf(2.0f * pz / den);
    float phi = atan2f(py, px);
    prep[(size_t)idx*3 + 0] = pt;
    prep[(size_t)idx*3 + 1] = rap;
    prep[(size_t)idx*3 + 2] = phi;
    kpm[idx] = (x[(size_t)idx * FIN_] == 0.0f) ? 1.0f : 0.0f;
}

// ---------------- embed layer 1: LN16(x*BN) @ w0.T + b0, gelu ----------------
__global__ __launch_bounds__(256) void embed1_kernel(
    const float* __restrict__ x, const float* __restrict__ w0,
    const float* __restrict__ b0, float* __restrict__ e1)
{
    __shared__ float xs[2][16];
    __shared__ float ms[2], rss[2];
    int tid = threadIdx.x;
    int t0 = blockIdx.x * 2;
    if (tid < 32) {
        int t = tid >> 4, kk = tid & 15;
        xs[t][kk] = x[(size_t)(t0 + t) * FIN_ + kk] * BN_SCALE_F;
    }
    __syncthreads();
    if (tid < 2) {
        float s = 0.f;
        #pragma unroll
        for (int kk = 0; kk < 16; ++kk) s += xs[tid][kk];
        float m = s * (1.f/16.f);
        float vs = 0.f;
        #pragma unroll
        for (int kk = 0; kk < 16; ++kk) { float d = xs[tid][kk] - m; vs += d*d; }
        ms[tid] = m;
        rss[tid] = rsqrtf(vs * (1.f/16.f) + EPSF);
    }
    __syncthreads();
    int t = tid >> 7, o = tid & 127;
    float m = ms[t], r = rss[t];
    float acc = b0[o];
    #pragma unroll
    for (int kk = 0; kk < 16; ++kk)
        acc += w0[o*16 + kk] * ((xs[t][kk] - m) * r);
    e1[(size_t)(t0 + t)*128 + o] = gelu_f(acc);
}

// ---------------- generic MFMA linear (verified r2 template) ----------------
template<int ACT, bool HASRES>
__global__ __launch_bounds__(256) void linmm_kernel(
    const float* __restrict__ in, const float* __restrict__ w,
    const float* __restrict__ bias, float* __restrict__ out,
    const float* __restrict__ res, const float* __restrict__ lam,
    int N, int K, int Dout)
{
    __shared__ __align__(16) short As[64*64];
    __shared__ __align__(16) short Bs[64*64];
    int tid = threadIdx.x;
    int n0 = blockIdx.x * 64, o0 = blockIdx.y * 64;
    int lane = tid & 63, wv = tid >> 6;
    int srow = tid >> 2, scc = tid & 3;
    const float* ain = in + (size_t)(n0 + srow)*K + scc*16;
    const float* bin = w  + (size_t)(o0 + srow)*K + scc*16;
    float4v acc[4];
    #pragma unroll
    for (int n = 0; n < 4; ++n) acc[n] = (float4v){0.f,0.f,0.f,0.f};
    int c0 = scc * 2;
    int swz = srow & 7;
    int wrb = srow * 64;
    int arow = (wv << 4) + (lane & 15);
    int kgrp = lane >> 4;

    for (int k0 = 0; k0 < K; k0 += 64) {
        float4 a0 = *(const float4*)(ain + k0);
        float4 a1 = *(const float4*)(ain + k0 + 4);
        float4 a2 = *(const float4*)(ain + k0 + 8);
        float4 a3 = *(const float4*)(ain + k0 + 12);
        float4 g0 = *(const float4*)(bin + k0);
        float4 g1 = *(const float4*)(bin + k0 + 4);
        float4 g2 = *(const float4*)(bin + k0 + 8);
        float4 g3 = *(const float4*)(bin + k0 + 12);
        __syncthreads();
        short8v sa0, sa1, sb0, sb1;
        sa0[0]=f2b(a0.x); sa0[1]=f2b(a0.y); sa0[2]=f2b(a0.z); sa0[3]=f2b(a0.w);
        sa0[4]=f2b(a1.x); sa0[5]=f2b(a1.y); sa0[6]=f2b(a1.z); sa0[7]=f2b(a1.w);
        sa1[0]=f2b(a2.x); sa1[1]=f2b(a2.y); sa1[2]=f2b(a2.z); sa1[3]=f2b(a2.w);
        sa1[4]=f2b(a3.x); sa1[5]=f2b(a3.y); sa1[6]=f2b(a3.z); sa1[7]=f2b(a3.w);
        sb0[0]=f2b(g0.x); sb0[1]=f2b(g0.y); sb0[2]=f2b(g0.z); sb0[3]=f2b(g0.w);
        sb0[4]=f2b(g1.x); sb0[5]=f2b(g1.y); sb0[6]=f2b(g1.z); sb0[7]=f2b(g1.w);
        sb1[0]=f2b(g2.x); sb1[1]=f2b(g2.y); sb1[2]=f2b(g2.z); sb1[3]=f2b(g2.w);
        sb1[4]=f2b(g3.x); sb1[5]=f2b(g3.y); sb1[6]=f2b(g3.z); sb1[7]=f2b(g3.w);
        *(short8v*)&As[wrb + (((c0    ) ^ swz) << 3)] = sa0;
        *(short8v*)&As[wrb + (((c0 + 1) ^ swz) << 3)] = sa1;
        *(short8v*)&Bs[wrb + (((c0    ) ^ swz) << 3)] = sb0;
        *(short8v*)&Bs[wrb + (((c0 + 1) ^ swz) << 3)] = sb1;
        __syncthreads();
        #pragma unroll
        for (int ks = 0; ks < 2; ++ks) {
            int ch = (ks << 2) | kgrp;
            short8v av = *(short8v*)&As[arow*64 + ((ch ^ (arow & 7)) << 3)];
            #pragma unroll
            for (int n = 0; n < 4; ++n) {
                int brow = (n << 4) + (lane & 15);
                short8v bv = *(short8v*)&Bs[brow*64 + ((ch ^ (brow & 7)) << 3)];
                acc[n] = __builtin_amdgcn_mfma_f32_16x16x32_bf16(av, bv, acc[n], 0, 0, 0);
            }
        }
    }
    int colb = lane & 15, rgrp = lane >> 4;
    #pragma unroll
    for (int n = 0; n < 4; ++n) {
        int oo = o0 + (n << 4) + colb;
        float bvv = bias ? bias[oo] : 0.f;
        float lm = HASRES ? lam[oo] : 0.f;
        #pragma unroll
        for (int r = 0; r < 4; ++r) {
            int nn = n0 + (wv << 4) + (rgrp << 2) + r;
            float v = acc[n][r] + bvv;
            if (ACT == 1) v = gelu_f(v);
            if (HASRES) v += lm * res[(size_t)nn*Dout + oo];
            out[(size_t)nn*Dout + oo] = v;
        }
    }
}

// ---------------- QKV all-in-one: A staged once, Q/K/V sequential ----------------
// grid NT/64. Block: 64 rows x Dout=128 per weight; K=128.
__global__ __launch_bounds__(256) void qkvall_kernel(
    const float* __restrict__ in,
    const float* __restrict__ wq, const float* __restrict__ wk, const float* __restrict__ wv,
    float* __restrict__ qo, float* __restrict__ ko, float* __restrict__ vo)
{
    __shared__ __align__(16) short As[64*128];
    __shared__ __align__(16) short Bs[128*64];
    int tid = threadIdx.x;
    int n0 = blockIdx.x * 64;
    int srow = tid >> 2, scc = tid & 3;
    int lane = tid & 63, w4 = tid >> 6;
    int l15 = lane & 15, kgrp = lane >> 4;

    {   // stage A [64][128] bf16 swizzled (fc1_ln pattern, no LN)
        const float* ap = in + (size_t)(n0 + srow)*128 + scc*32;
        #pragma unroll
        for (int c = 0; c < 4; ++c) {
            float4 t0 = *(const float4*)(ap + c*8);
            float4 t1 = *(const float4*)(ap + c*8 + 4);
            short8v sv;
            sv[0]=f2b(t0.x); sv[1]=f2b(t0.y); sv[2]=f2b(t0.z); sv[3]=f2b(t0.w);
            sv[4]=f2b(t1.x); sv[5]=f2b(t1.y); sv[6]=f2b(t1.z); sv[7]=f2b(t1.w);
            int cc = scc*4 + c;
            *(short8v*)&As[srow*128 + ((cc ^ (srow & 7)) << 3)] = sv;
        }
    }
    __syncthreads();
    int arow = (w4 << 4) + l15;
    short8v aF[4];
    #pragma unroll
    for (int ks = 0; ks < 4; ++ks) {
        int ch = ks*4 + kgrp;
        aF[ks] = *(short8v*)&As[arow*128 + ((ch ^ (arow & 7)) << 3)];
    }

    int brow2 = tid >> 1, half = tid & 1;
    #pragma unroll
    for (int wsel = 0; wsel < 3; ++wsel) {
        const float* w   = (wsel == 0) ? wq : (wsel == 1) ? wk : wv;
        float*       out = (wsel == 0) ? qo : (wsel == 1) ? ko : vo;
        float4v acc[8];
        #pragma unroll
        for (int n = 0; n < 8; ++n) acc[n] = (float4v){0.f,0.f,0.f,0.f};
        #pragma unroll
        for (int c2 = 0; c2 < 2; ++c2) {
            // load B chunk to regs
            const float* bp = w + (size_t)brow2*128 + c2*64 + half*32;
            float4 t[8];
            #pragma unroll
            for (int c = 0; c < 8; ++c) t[c] = *(const float4*)(bp + c*4);
            __syncthreads();   // prev Bs consumed
            #pragma unroll
            for (int c = 0; c < 4; ++c) {
                short8v sv;
                sv[0]=f2b(t[c*2].x);   sv[1]=f2b(t[c*2].y);   sv[2]=f2b(t[c*2].z);   sv[3]=f2b(t[c*2].w);
                sv[4]=f2b(t[c*2+1].x); sv[5]=f2b(t[c*2+1].y); sv[6]=f2b(t[c*2+1].z); sv[7]=f2b(t[c*2+1].w);
                int cc = half*4 + c;
                *(short8v*)&Bs[brow2*64 + ((cc ^ (brow2 & 7)) << 3)] = sv;
            }
            __syncthreads();
            #pragma unroll
            for (int ksl = 0; ksl < 2; ++ksl) {
                int chb = ksl*4 + kgrp;
                short8v av = aF[c2*2 + ksl];
                #pragma unroll
                for (int n = 0; n < 8; ++n) {
                    int brow = n*16 + l15;
                    short8v bv = *(short8v*)&Bs[brow*64 + ((chb ^ (brow & 7)) << 3)];
                    acc[n] = __builtin_amdgcn_mfma_f32_16x16x32_bf16(av, bv, acc[n], 0, 0, 0);
                }
            }
        }
        #pragma unroll
        for (int n = 0; n < 8; ++n) {
            int col = n*16 + l15;
            #pragma unroll
            for (int r = 0; r < 4; ++r) {
                int row = n0 + (w4 << 4) + (kgrp << 2) + r;
                out[(size_t)row*128 + col] = acc[n][r];
            }
        }
    }
}

// ---------------- fused FC2 + bias + lam*res + (next-layer LN) ----------------
// out_xp = in @ w.T + b + lam*res;  if EMITLN: out_ln = LN(out_xp)*g + bb.
// grid N/64, 256 thr; K=512, Dout=128 full rows per block.
template<bool EMITLN>
__global__ __launch_bounds__(256) void fc2_ln_kernel(
    const float* __restrict__ in, const float* __restrict__ w,
    const float* __restrict__ bias2, const float* __restrict__ lam,
    const float* __restrict__ res, float* __restrict__ out_xp,
    const float* __restrict__ lng, const float* __restrict__ lnb,
    float* __restrict__ out_ln)
{
    __shared__ __align__(16) short As[64*64];
    __shared__ __align__(16) short Bs[128*64];
    __shared__ float biass[128], lams[128], gs[128], bs[128];
    int tid = threadIdx.x;
    int n0 = blockIdx.x * 64;
    int srow = tid >> 2, scc = tid & 3;
    int brow2 = tid >> 1, half = tid & 1;
    int lane = tid & 63, w4 = tid >> 6;
    int l15 = lane & 15, kgrp = lane >> 4;

    if (tid < 128) {
        biass[tid] = bias2[tid];
        lams[tid]  = lam[tid];
        if (EMITLN) { gs[tid] = lng[tid]; bs[tid] = lnb[tid]; }
    }

    float4v acc[8];
    #pragma unroll
    for (int n = 0; n < 8; ++n) acc[n] = (float4v){0.f,0.f,0.f,0.f};

    for (int c8 = 0; c8 < 8; ++c8) {
        // global loads first (linmm pattern)
        const float* ap = in + (size_t)(n0 + srow)*512 + c8*64 + scc*16;
        float4 a0 = *(const float4*)(ap);
        float4 a1 = *(const float4*)(ap + 4);
        float4 a2 = *(const float4*)(ap + 8);
        float4 a3 = *(const float4*)(ap + 12);
        const float* bp = w + (size_t)brow2*512 + c8*64 + half*32;
        float4 t[8];
        #pragma unroll
        for (int c = 0; c < 8; ++c) t[c] = *(const float4*)(bp + c*4);
        __syncthreads();   // prev tile consumed
        {
            short8v sa0, sa1;
            sa0[0]=f2b(a0.x); sa0[1]=f2b(a0.y); sa0[2]=f2b(a0.z); sa0[3]=f2b(a0.w);
            sa0[4]=f2b(a1.x); sa0[5]=f2b(a1.y); sa0[6]=f2b(a1.z); sa0[7]=f2b(a1.w);
            sa1[0]=f2b(a2.x); sa1[1]=f2b(a2.y); sa1[2]=f2b(a2.z); sa1[3]=f2b(a2.w);
            sa1[4]=f2b(a3.x); sa1[5]=f2b(a3.y); sa1[6]=f2b(a3.z); sa1[7]=f2b(a3.w);
            int c0 = scc*2;
            *(short8v*)&As[srow*64 + (((c0    ) ^ (srow & 7)) << 3)] = sa0;
            *(short8v*)&As[srow*64 + (((c0 + 1) ^ (srow & 7)) << 3)] = sa1;
            #pragma unroll
            for (int c = 0; c < 4; ++c) {
                short8v sv;
                sv[0]=f2b(t[c*2].x);   sv[1]=f2b(t[c*2].y);   sv[2]=f2b(t[c*2].z);   sv[3]=f2b(t[c*2].w);
                sv[4]=f2b(t[c*2+1].x); sv[5]=f2b(t[c*2+1].y); sv[6]=f2b(t[c*2+1].z); sv[7]=f2b(t[c*2+1].w);
                int cc = half*4 + c;
                *(short8v*)&Bs[brow2*64 + ((cc ^ (brow2 & 7)) << 3)] = sv;
            }
        }
        __syncthreads();
        int arow = (w4 << 4) + l15;
        #pragma unroll
        for (int ks = 0; ks < 2; ++ks) {
            int ch = ks*4 + kgrp;
            short8v av = *(short8v*)&As[arow*64 + ((ch ^ (arow & 7)) << 3)];
            #pragma unroll
            for (int n = 0; n < 8; ++n) {
                int brow = n*16 + l15;
                short8v bv = *(short8v*)&Bs[brow*64 + ((ch ^ (brow & 7)) << 3)];
                acc[n] = __builtin_amdgcn_mfma_f32_16x16x32_bf16(av, bv, acc[n], 0, 0, 0);
            }
        }
    }

    // epilogue: v = acc + bias + lam*res; write xp; optional LN -> out_ln
    float v[8][4];
    #pragma unroll
    for (int n = 0; n < 8; ++n) {
        int col = n*16 + l15;
        float bvv = biass[col], lm = lams[col];
        #pragma unroll
        for (int r = 0; r < 4; ++r) {
            size_t row = (size_t)(n0 + (w4 << 4) + (kgrp << 2) + r);
            float vv = acc[n][r] + bvv + lm * res[row*128 + col];
            v[n][r] = vv;
            out_xp[row*128 + col] = vv;
        }
    }
    if (EMITLN) {
        #pragma unroll
        for (int r = 0; r < 4; ++r) {
            float s = 0.f, sq = 0.f;
            #pragma unroll
            for (int n = 0; n < 8; ++n) { float vv = v[n][r]; s += vv; sq += vv*vv; }
            s  += __shfl_xor(s, 1);  s  += __shfl_xor(s, 2);  s  += __shfl_xor(s, 4);  s  += __shfl_xor(s, 8);
            sq += __shfl_xor(sq, 1); sq += __shfl_xor(sq, 2); sq += __shfl_xor(sq, 4); sq += __shfl_xor(sq, 8);
            float mean = s * (1.f/128.f);
            float var = sq * (1.f/128.f) - mean*mean;
            float rs = rsqrtf(fmaxf(var, 0.f) + EPSF);
            size_t row = (size_t)(n0 + (w4 << 4) + (kgrp << 2) + r);
            #pragma unroll
            for (int n = 0; n < 8; ++n) {
                int col = n*16 + l15;
                out_ln[row*128 + col] = (v[n][r] - mean) * rs * gs[col] + bs[col];
            }
        }
    }
}

// ---------------- fused WO gemm + LN + residual (proven r7) ----------------
__global__ __launch_bounds__(256) void wo_ln_kernel(
    const float* __restrict__ in, const float* __restrict__ w,
    const float* __restrict__ g, const float* __restrict__ bb,
    const float* __restrict__ res, float* __restrict__ out)
{
    __shared__ __align__(16) short As[64*128];
    __shared__ __align__(16) short Bs[128*128];
    __shared__ float gs[128], bs[128];
    __shared__ float parts[2][64][2];
    int tid = threadIdx.x;
    int n0 = blockIdx.x * 64;

    if (tid < 128) gs[tid] = g[tid];
    else bs[tid - 128] = bb[tid - 128];

    {
        int srow = tid >> 2, scc = tid & 3;
        const float* ap = in + (size_t)(n0 + srow)*128 + scc*32;
        #pragma unroll
        for (int c = 0; c < 4; ++c) {
            float4 t0 = *(const float4*)(ap + c*8);
            float4 t1 = *(const float4*)(ap + c*8 + 4);
            short8v sv;
            sv[0]=f2b(t0.x); sv[1]=f2b(t0.y); sv[2]=f2b(t0.z); sv[3]=f2b(t0.w);
            sv[4]=f2b(t1.x); sv[5]=f2b(t1.y); sv[6]=f2b(t1.z); sv[7]=f2b(t1.w);
            int cc = scc*4 + c;
            *(short8v*)&As[srow*128 + ((cc ^ (srow & 7)) << 3)] = sv;
        }
    }
    {
        int brow = tid & 127, bh = tid >> 7;
        const float* bp = w + (size_t)brow*128 + bh*64;
        #pragma unroll
        for (int c = 0; c < 8; ++c) {
            float4 t0 = *(const float4*)(bp + c*8);
            float4 t1 = *(const float4*)(bp + c*8 + 4);
            short8v sv;
            sv[0]=f2b(t0.x); sv[1]=f2b(t0.y); sv[2]=f2b(t0.z); sv[3]=f2b(t0.w);
            sv[4]=f2b(t1.x); sv[5]=f2b(t1.y); sv[6]=f2b(t1.z); sv[7]=f2b(t1.w);
            int cc = bh*8 + c;
            *(short8v*)&Bs[brow*128 + ((cc ^ (brow & 7)) << 3)] = sv;
        }
    }
    __syncthreads();

    int lane = tid & 63, w4 = tid >> 6;
    int l15 = lane & 15, kgrp = lane >> 4;
    int rw = w4 >> 1, cw = w4 & 1;
    float4v acc[2][4];
    #pragma unroll
    for (int m = 0; m < 2; ++m)
        #pragma unroll
        for (int n = 0; n < 4; ++n) acc[m][n] = (float4v){0.f,0.f,0.f,0.f};
    #pragma unroll
    for (int ks = 0; ks < 4; ++ks) {
        int ch = ks*4 + kgrp;
        short8v av[2];
        #pragma unroll
        for (int m = 0; m < 2; ++m) {
            int arow = rw*32 + m*16 + l15;
            av[m] = *(short8v*)&As[arow*128 + ((ch ^ (arow & 7)) << 3)];
        }
        #pragma unroll
        for (int n = 0; n < 4; ++n) {
            int brow = cw*64 + n*16 + l15;
            short8v bv = *(short8v*)&Bs[brow*128 + ((ch ^ (brow & 7)) << 3)];
            #pragma unroll
            for (int m = 0; m < 2; ++m)
                acc[m][n] = __builtin_amdgcn_mfma_f32_16x16x32_bf16(av[m], bv, acc[m][n], 0, 0, 0);
        }
    }
    #pragma unroll
    for (int m = 0; m < 2; ++m) {
        #pragma unroll
        for (int r = 0; r < 4; ++r) {
            float s = acc[m][0][r] + acc[m][1][r] + acc[m][2][r] + acc[m][3][r];
            float sq = acc[m][0][r]*acc[m][0][r] + acc[m][1][r]*acc[m][1][r]
                     + acc[m][2][r]*acc[m][2][r] + acc[m][3][r]*acc[m][3][r];
            s  += __shfl_xor(s, 1);  s  += __shfl_xor(s, 2);  s  += __shfl_xor(s, 4);  s  += __shfl_xor(s, 8);
            sq += __shfl_xor(sq, 1); sq += __shfl_xor(sq, 2); sq += __shfl_xor(sq, 4); sq += __shfl_xor(sq, 8);
            if (l15 == 0) {
                int rl = rw*32 + m*16 + kgrp*4 + r;
                parts[cw][rl][0] = s;
                parts[cw][rl][1] = sq;
            }
        }
    }
    __syncthreads();
    #pragma unroll
    for (int m = 0; m < 2; ++m) {
        int rl_base = rw*32 + m*16 + kgrp*4;
        #pragma unroll
        for (int r = 0; r < 4; ++r) {
            int rl = rl_base + r;
            float st = parts[0][rl][0] + parts[1][rl][0];
            float sqt = parts[0][rl][1] + parts[1][rl][1];
            float mean = st * (1.f/128.f);
            float var = sqt * (1.f/128.f) - mean*mean;
            float rs = rsqrtf(fmaxf(var, 0.f) + EPSF);
            size_t rowg = (size_t)(n0 + rl);
            #pragma unroll
            for (int n = 0; n < 4; ++n) {
                int col = cw*64 + n*16 + l15;
                float v = (acc[m][n][r] - mean) * rs * gs[col] + bs[col] + res[rowg*128 + col];
                out[rowg*128 + col] = v;
            }
        }
    }
}

// ---------------- fused LN-in + FC1 + GELU + LN512-out (proven r6) ----------------
__global__ __launch_bounds__(256) void fc1_ln_kernel(
    const float* __restrict__ in,
    const float* __restrict__ g, const float* __restrict__ bb,
    const float* __restrict__ w1, const float* __restrict__ b1,
    const float* __restrict__ lg, const float* __restrict__ lb,
    float* __restrict__ out)
{
    __shared__ __align__(16) short As[64*128];
    __shared__ __align__(16) short BUF[64*128];
    __shared__ float gs[128], bs[128];
    __shared__ float bs1[512], lgs[512], lbs[512];
    int tid = threadIdx.x;
    int n0 = blockIdx.x * 64;
    int srow = tid >> 2, scc = tid & 3;

    if (tid < 128) gs[tid] = g ? g[tid] : 1.f;
    else bs[tid - 128] = bb ? bb[tid - 128] : 0.f;
    for (int idx = tid; idx < 512; idx += 256) {
        bs1[idx] = b1[idx];
        lgs[idx] = lg ? lg[idx] : 1.f;
        lbs[idx] = lb ? lb[idx] : 0.f;
    }

    {   // A: LN staging (one-pass stats across 4 lanes/row)
        const float* ap = in + (size_t)(n0 + srow)*128 + scc*32;
        float vals[32];
        float s = 0.f, sq = 0.f;
        #pragma unroll
        for (int q8 = 0; q8 < 8; ++q8) {
            float4 t4 = *(const float4*)(ap + q8*4);
            vals[q8*4+0]=t4.x; vals[q8*4+1]=t4.y; vals[q8*4+2]=t4.z; vals[q8*4+3]=t4.w;
            s += t4.x + t4.y + t4.z + t4.w;
            sq += t4.x*t4.x + t4.y*t4.y + t4.z*t4.z + t4.w*t4.w;
        }
        s  += __shfl_xor(s, 1);  s  += __shfl_xor(s, 2);
        sq += __shfl_xor(sq, 1); sq += __shfl_xor(sq, 2);
        float mean = s * (1.f/128.f);
        float var = sq * (1.f/128.f) - mean*mean;
        float rs = rsqrtf(fmaxf(var, 0.f) + EPSF);
        __syncthreads();   // gs/bs visible
        #pragma unroll
        for (int c = 0; c < 4; ++c) {
            short8v sv;
            #pragma unroll
            for (int e = 0; e < 8; ++e) {
                int k = scc*32 + c*8 + e;
                sv[e] = f2b((vals[c*8+e] - mean) * rs * gs[k] + bs[k]);
            }
            int cc = scc*4 + c;
            *(short8v*)&As[srow*128 + ((cc ^ (srow & 7)) << 3)] = sv;
        }
    }
    __syncthreads();

    int lane = tid & 63, w4 = tid >> 6;
    int l15 = lane & 15, kgrp = lane >> 4;
    int arow = (w4 << 4) + l15;
    short8v aF[4];
    #pragma unroll
    for (int ks = 0; ks < 4; ++ks) {
        int ch = ks*4 + kgrp;
        aF[ks] = *(short8v*)&As[arow*128 + ((ch ^ (arow & 7)) << 3)];
    }
    float4v acc[32];
    #pragma unroll
    for (int n = 0; n < 32; ++n) acc[n] = (float4v){0.f,0.f,0.f,0.f};

    #pragma unroll
    for (int c8 = 0; c8 < 8; ++c8) {
        __syncthreads();
        {
            const float* bp = w1 + (size_t)(c8*64 + srow)*128 + scc*32;
            #pragma unroll
            for (int c = 0; c < 4; ++c) {
                float4 t0 = *(const float4*)(bp + c*8);
                float4 t1 = *(const float4*)(bp + c*8 + 4);
                short8v sv;
                sv[0]=f2b(t0.x); sv[1]=f2b(t0.y); sv[2]=f2b(t0.z); sv[3]=f2b(t0.w);
                sv[4]=f2b(t1.x); sv[5]=f2b(t1.y); sv[6]=f2b(t1.z); sv[7]=f2b(t1.w);
                int cc = scc*4 + c;
                *(short8v*)&BUF[srow*128 + ((cc ^ (srow & 7)) << 3)] = sv;
            }
        }
        __syncthreads();
        #pragma unroll
        for (int ks = 0; ks < 4; ++ks) {
            int ch = ks*4 + kgrp;
            #pragma unroll
            for (int n = 0; n < 4; ++n) {
                int brow = n*16 + l15;
                short8v bv = *(short8v*)&BUF[brow*128 + ((ch ^ (brow & 7)) << 3)];
                acc[c8*4+n] = __builtin_amdgcn_mfma_f32_16x16x32_bf16(aF[ks], bv, acc[c8*4+n], 0, 0, 0);
            }
        }
    }

    #pragma unroll
    for (int nf = 0; nf < 32; ++nf) {
        int col = nf*16 + l15;
        #pragma unroll
        for (int r = 0; r < 4; ++r)
            acc[nf][r] = gelu_f(acc[nf][r] + bs1[col]);
    }
    float mean[4], rsv[4];
    #pragma unroll
    for (int r = 0; r < 4; ++r) {
        float s = 0.f, sq = 0.f;
        #pragma unroll
        for (int nf = 0; nf < 32; ++nf) { float v = acc[nf][r]; s += v; sq += v*v; }
        s  += __shfl_xor(s, 1);  s  += __shfl_xor(s, 2);  s  += __shfl_xor(s, 4);  s  += __shfl_xor(s, 8);
        sq += __shfl_xor(sq, 1); sq += __shfl_xor(sq, 2); sq += __shfl_xor(sq, 4); sq += __shfl_xor(sq, 8);
        mean[r] = s * (1.f/512.f);
        float var = sq * (1.f/512.f) - mean[r]*mean[r];
        rsv[r] = rsqrtf(fmaxf(var, 0.f) + EPSF);
    }
    #pragma unroll
    for (int r = 0; r < 4; ++r) {
        size_t rowg = (size_t)(n0 + (w4 << 4) + (kgrp << 2) + r);
        #pragma unroll
        for (int nf = 0; nf < 32; ++nf) {
            int col = nf*16 + l15;
            out[rowg*512 + col] = (acc[nf][r] - mean[r]) * rsv[r] * lgs[col] + lbs[col];
        }
    }
}

// ---------------- interaction bias: dual-MFMA (proven r6) ----------------
__global__ __launch_bounds__(256) void bias_kernel(
    const float* __restrict__ p4, const float* __restrict__ prep,
    const float* __restrict__ w0, const float* __restrict__ b0,
    const float* __restrict__ w1, const float* __restrict__ b1,
    const float* __restrict__ w2, const float* __restrict__ b2,
    __hip_bfloat16* __restrict__ bias)
{
    __shared__ float pj[128][8];
    __shared__ float w0s[256], b0s[64], b1s[64], b2s[8];
    __shared__ __align__(16) short U[256*64];
    __shared__ __align__(16) short W1s[64*64];
    __shared__ __align__(16) short W2s[16*64];
    __shared__ short si[256], sj[256];
    int tid = threadIdx.x;
    int b  = blockIdx.x / 33;
    int p  = (blockIdx.x % 33) * 256 + tid;

    w0s[tid] = w0[tid];
    if (tid < 64) { b0s[tid] = b0[tid]; b1s[tid] = b1[tid]; }
    if (tid < 8)  b2s[tid] = b2[tid];
    {
        int o = tid >> 2;
        const float* wp = w1 + o*64 + (tid & 3) * 16;
        #pragma unroll
        for (int h2 = 0; h2 < 2; ++h2) {
            float4 t0 = *(const float4*)(wp + h2*8);
            float4 t1 = *(const float4*)(wp + h2*8 + 4);
            short8v sv;
            sv[0]=f2b(t0.x); sv[1]=f2b(t0.y); sv[2]=f2b(t0.z); sv[3]=f2b(t0.w);
            sv[4]=f2b(t1.x); sv[5]=f2b(t1.y); sv[6]=f2b(t1.z); sv[7]=f2b(t1.w);
            int cc = (tid & 3)*2 + h2;
            *(short8v*)&W1s[o*64 + ((cc ^ (o & 7)) << 3)] = sv;
        }
    }
    if (tid < 128) {
        int o2 = tid >> 3, c = tid & 7;
        short8v sv;
        #pragma unroll
        for (int e = 0; e < 8; ++e)
            sv[e] = (o2 < 8) ? f2b(w2[o2*64 + c*8 + e]) : (short)0;
        *(short8v*)&W2s[o2*64 + ((c ^ (o2 & 7)) << 3)] = sv;
    }
    if (tid < 128) {
        int s = tid;
        const float* pr = prep + ((size_t)b*S_ + s)*3;
        pj[s][0] = pr[0]; pj[s][1] = pr[1]; pj[s][2] = pr[2];
        const float* pp = p4 + ((size_t)b*S_ + s)*4;
        pj[s][3] = pp[0]; pj[s][4] = pp[1]; pj[s][5] = pp[2]; pj[s][6] = pp[3];
    }

    bool valid = p < 8256;
    int i = 0, j = 0;
    if (valid) {
        i = (int)((257.0f - sqrtf((float)(66049 - 8*p))) * 0.5f);
        if (i > 127) i = 127;
        if (i < 0) i = 0;
        while (i > 0 && i*(257 - i)/2 > p) --i;
        while ((i + 1)*(257 - (i + 1))/2 <= p) ++i;
        j = i + (p - i*(257 - i)/2);
    }
    si[tid] = (short)(valid ? i : -1);
    sj[tid] = (short)j;
    __syncthreads();

    float pti = pj[i][0], rapi = pj[i][1], phii = pj[i][2];
    float pxi = pj[i][3], pyi = pj[i][4], pzi = pj[i][5], ei = pj[i][6];
    float ptj = pj[j][0], rapj = pj[j][1], phij = pj[j][2];
    float pxj = pj[j][3], pyj = pj[j][4], pzj = pj[j][5], ej = pj[j][6];

    float dph = phij - phii + PI_F;
    dph = dph - floorf(dph * INV_TWO_PI_F) * TWO_PI_F;
    dph -= PI_F;
    float drap = rapi - rapj;
    float delta = fmaxf(sqrtf(drap*drap + dph*dph), 1e-8f);
    float ptmin = fminf(pti, ptj);
    float kt = fmaxf(ptmin * delta, 1e-8f);
    float z  = fmaxf(ptmin / fmaxf(pti + ptj, 1e-8f), 1e-8f);
    float es = ei + ej, pxs = pxi + pxj, pys = pyi + pyj, pzs = pzi + pzj;
    float m2 = fmaxf(es*es - pxs*pxs - pys*pys - pzs*pzs, 1e-8f);

    float f0 = logf(delta) * BN_SCALE_F;
    float f1 = logf(kt)    * BN_SCALE_F;
    float f2 = logf(z)     * BN_SCALE_F;
    float f3 = logf(m2)    * BN_SCALE_F;

    #pragma unroll
    for (int c8 = 0; c8 < 8; ++c8) {
        short8v sv;
        #pragma unroll
        for (int e = 0; e < 8; ++e) {
            int o = c8*8 + e;
            float a = b0s[o] + w0s[o*4+0]*f0 + w0s[o*4+1]*f1 + w0s[o*4+2]*f2 + w0s[o*4+3]*f3;
            sv[e] = f2b(gelu_fast(a * BN_SCALE_F));
        }
        *(short8v*)&U[tid*64 + ((c8 ^ (tid & 7)) << 3)] = sv;
    }
    __syncthreads();

    int lane = tid & 63, w4 = tid >> 6;
    int l15 = lane & 15, kgrp = lane >> 4;
    float4v acc[4][4];
    #pragma unroll
    for (int m = 0; m < 4; ++m)
        #pragma unroll
        for (int n = 0; n < 4; ++n) acc[m][n] = (float4v){0.f,0.f,0.f,0.f};
    #pragma unroll
    for (int ks = 0; ks < 2; ++ks) {
        int ch = ks*4 + kgrp;
        #pragma unroll
        for (int m = 0; m < 4; ++m) {
            int arow = w4*64 + m*16 + l15;
            short8v av = *(short8v*)&U[arow*64 + ((ch ^ (arow & 7)) << 3)];
            #pragma unroll
            for (int n = 0; n < 4; ++n) {
                int brow = n*16 + l15;
                short8v bv = *(short8v*)&W1s[brow*64 + ((ch ^ (brow & 7)) << 3)];
                acc[m][n] = __builtin_amdgcn_mfma_f32_16x16x32_bf16(av, bv, acc[m][n], 0, 0, 0);
            }
        }
    }

    #pragma unroll
    for (int m = 0; m < 4; ++m) {
        #pragma unroll
        for (int n = 0; n < 4; ++n) {
            int o = n*16 + l15;
            #pragma unroll
            for (int r = 0; r < 4; ++r) {
                int row = w4*64 + m*16 + kgrp*4 + r;
                float u2 = gelu_fast((acc[m][n][r] + b1s[o]) * BN_SCALE_F);
                U[row*64 + (((o >> 3) ^ (row & 7)) << 3) + (o & 7)] = f2b(u2);
            }
        }
    }

    float4v acc2[4];
    #pragma unroll
    for (int m = 0; m < 4; ++m) acc2[m] = (float4v){0.f,0.f,0.f,0.f};
    #pragma unroll
    for (int ks = 0; ks < 2; ++ks) {
        int ch = ks*4 + kgrp;
        short8v bv = *(short8v*)&W2s[l15*64 + ((ch ^ (l15 & 7)) << 3)];
        #pragma unroll
        for (int m = 0; m < 4; ++m) {
            int arow = w4*64 + m*16 + l15;
            short8v av = *(short8v*)&U[arow*64 + ((ch ^ (arow & 7)) << 3)];
            acc2[m] = __builtin_amdgcn_mfma_f32_16x16x32_bf16(av, bv, acc2[m], 0, 0, 0);
        }
    }

    size_t base = ((size_t)b*H_)*S_*S_;
    #pragma unroll
    for (int m = 0; m < 4; ++m) {
        #pragma unroll
        for (int r = 0; r < 4; ++r) {
            int row = w4*64 + m*16 + kgrp*4 + r;
            int ii = si[row], jj = sj[row];
            if (l15 < 8 && ii >= 0) {
                float v = gelu_fast((acc2[m][r] + b2s[l15]) * BN_SCALE_F);
                __hip_bfloat16 bv16 = __float2bfloat16(v);
                bias[base + (size_t)l15*S_*S_ + (size_t)ii*S_ + jj] = bv16;
                bias[base + (size_t)l15*S_*S_ + (size_t)jj*S_ + ii] = bv16;
            }
        }
    }
}

// ---------------- generic LayerNorm (64 threads/row) ----------------
template<int W>
__global__ __launch_bounds__(64) void ln_kernel(
    const float* __restrict__ in, float* __restrict__ out,
    const float* __restrict__ g, const float* __restrict__ bb,
    const float* __restrict__ res)
{
    constexpr int E = W / 64;
    int row = blockIdx.x;
    int lane = threadIdx.x;
    const float* r = in + (size_t)row * W;
    float vals[E];
    float s = 0.f;
    #pragma unroll
    for (int e = 0; e < E; ++e) { vals[e] = r[lane + 64*e]; s += vals[e]; }
    #pragma unroll
    for (int o = 32; o > 0; o >>= 1) s += __shfl_xor(s, o);
    float m = s * (1.f / W);
    float vsum = 0.f;
    #pragma unroll
    for (int e = 0; e < E; ++e) { float d = vals[e] - m; vsum += d*d; }
    #pragma unroll
    for (int o = 32; o > 0; o >>= 1) vsum += __shfl_xor(vsum, o);
    float rs = rsqrtf(vsum * (1.f / W) + EPSF);
    #pragma unroll
    for (int e = 0; e < E; ++e) {
        int c = lane + 64*e;
        float v = (vals[e] - m) * rs;
        if (g) v = v * g[c] + bb[c];
        if (res) v += res[(size_t)row*W + c];
        out[(size_t)row*W + c] = v;
    }
}

// ---------------- MFMA particle attention per (b,h) (proven r8) ----------------
__global__ __launch_bounds__(256) void attn_kernel(
    const float* __restrict__ q, const float* __restrict__ k, const float* __restrict__ v,
    const __hip_bfloat16* __restrict__ bias, const float* __restrict__ kpm,
    const float* __restrict__ gam, int layer, float* __restrict__ out)
{
    int bh = blockIdx.x;
    int b = bh >> 3, h = bh & 7;
    __shared__ __align__(16) short qs[128][40];
    __shared__ __align__(16) short ks[128][40];
    __shared__ __align__(16) short vst[16][136];
    __shared__ __align__(16) short pb[64][136];
    int tid = threadIdx.x;

    {
        int r = tid >> 1, hh = tid & 1;
        const float* qp = q + ((size_t)(b*S_ + r))*D_ + h*16 + hh*8;
        const float* kp = k + ((size_t)(b*S_ + r))*D_ + h*16 + hh*8;
        float4 a0 = *(const float4*)qp;
        float4 a1 = *(const float4*)(qp + 4);
        float4 c0 = *(const float4*)kp;
        float4 c1 = *(const float4*)(kp + 4);
        short8v sq, sk, zz;
        sq[0]=f2b(a0.x); sq[1]=f2b(a0.y); sq[2]=f2b(a0.z); sq[3]=f2b(a0.w);
        sq[4]=f2b(a1.x); sq[5]=f2b(a1.y); sq[6]=f2b(a1.z); sq[7]=f2b(a1.w);
        sk[0]=f2b(c0.x); sk[1]=f2b(c0.y); sk[2]=f2b(c0.z); sk[3]=f2b(c0.w);
        sk[4]=f2b(c1.x); sk[5]=f2b(c1.y); sk[6]=f2b(c1.z); sk[7]=f2b(c1.w);
        #pragma unroll
        for (int e = 0; e < 8; ++e) zz[e] = 0;
        *(short8v*)&qs[r][hh*8] = sq;
        *(short8v*)&ks[r][hh*8] = sk;
        *(short8v*)&qs[r][16 + hh*8] = zz;
        *(short8v*)&ks[r][16 + hh*8] = zz;
    }
    {
        int j = tid >> 1, dg = (tid & 1)*8;
        const float* vp = v + ((size_t)(b*S_ + j))*D_ + h*16 + dg;
        float4 v0 = *(const float4*)vp;
        float4 v1 = *(const float4*)(vp + 4);
        vst[dg+0][j] = f2b(v0.x); vst[dg+1][j] = f2b(v0.y);
        vst[dg+2][j] = f2b(v0.z); vst[dg+3][j] = f2b(v0.w);
        vst[dg+4][j] = f2b(v1.x); vst[dg+5][j] = f2b(v1.y);
        vst[dg+6][j] = f2b(v1.z); vst[dg+7][j] = f2b(v1.w);
    }
    float gm = gam[layer*H_ + h];
    __syncthreads();

    int lane = tid & 63, w = tid >> 6;
    int l15 = lane & 15, l4 = lane >> 4;

    float msk[8];
    #pragma unroll
    for (int n = 0; n < 8; ++n) msk[n] = kpm[b*S_ + n*16 + l15];

    #pragma unroll
    for (int half = 0; half < 2; ++half) {
        int mrow = half*64 + w*16;
        short8v aq = *(short8v*)&qs[mrow + l15][l4*8];
        float4v sf[8];
        #pragma unroll
        for (int n = 0; n < 8; ++n) {
            short8v bk = *(short8v*)&ks[n*16 + l15][l4*8];
            sf[n] = __builtin_amdgcn_mfma_f32_16x16x32_bf16(aq, bk, (float4v){0.f,0.f,0.f,0.f}, 0, 0, 0);
        }
        #pragma unroll
        for (int r = 0; r < 4; ++r) {
            int srow = mrow + l4*4 + r;
            const __hip_bfloat16* bp = bias + ((size_t)(b*H_ + h)*S_ + srow)*S_ + l15;
            float sc[8];
            float mx = -1e30f;
            #pragma unroll
            for (int n = 0; n < 8; ++n) {
                float s = sf[n][r]*0.25f + __bfloat162float(bp[n*16]);
                if (msk[n] != 0.f) s = -1e30f;
                sc[n] = s;
                mx = fmaxf(mx, s);
            }
            mx = fmaxf(mx, __shfl_xor(mx, 1));
            mx = fmaxf(mx, __shfl_xor(mx, 2));
            mx = fmaxf(mx, __shfl_xor(mx, 4));
            mx = fmaxf(mx, __shfl_xor(mx, 8));
            float sum = 0.f;
            #pragma unroll
            for (int n = 0; n < 8; ++n) { float e = __expf(sc[n] - mx); sc[n] = e; sum += e; }
            sum += __shfl_xor(sum, 1);
            sum += __shfl_xor(sum, 2);
            sum += __shfl_xor(sum, 4);
            sum += __shfl_xor(sum, 8);
            float inv = 1.f / sum;
            int lrow = w*16 + l4*4 + r;
            #pragma unroll
            for (int n = 0; n < 8; ++n)
                pb[lrow][n*16 + l15] = f2b(sc[n] * inv);
        }
        float4v of = (float4v){0.f,0.f,0.f,0.f};
        #pragma unroll
        for (int ks4 = 0; ks4 < 4; ++ks4) {
            short8v pa = *(short8v*)&pb[w*16 + l15][ks4*32 + l4*8];
            short8v vb = *(short8v*)&vst[l15][ks4*32 + l4*8];
            of = __builtin_amdgcn_mfma_f32_16x16x32_bf16(pa, vb, of, 0, 0, 0);
        }
        #pragma unroll
        for (int r = 0; r < 4; ++r)
            out[((size_t)(b*S_ + mrow + l4*4 + r))*D_ + h*16 + l15] = of[r] * gm;
    }
}

// ---------------- class-token attention ----------------
__global__ __launch_bounds__(256) void cattn_kernel(
    const float* __restrict__ qc, const float* __restrict__ kc, const float* __restrict__ vc,
    const float* __restrict__ kpm, const float* __restrict__ gam,
    int layer, float* __restrict__ outc)
{
    int b = blockIdx.x / H_, h = blockIdx.x % H_;
    __shared__ float sc[132];
    int tid = threadIdx.x;
    const int T = S_ + 1;
    if (tid < T) {
        float acc = 0.f;
        #pragma unroll
        for (int d = 0; d < 16; ++d)
            acc += qc[(size_t)b*D_ + h*16 + d] * kc[((size_t)b*T + tid)*D_ + h*16 + d];
        acc *= 0.25f;
        if (tid > 0 && kpm[b*S_ + tid - 1] != 0.f) acc = -1e30f;
        sc[tid] = acc;
    }
    __syncthreads();
    if (tid == 0) {
        float m = -1e30f;
        for (int jj = 0; jj < T; ++jj) m = fmaxf(m, sc[jj]);
        float sum = 0.f;
        for (int jj = 0; jj < T; ++jj) { float e = __expf(sc[jj] - m); sc[jj] = e; sum += e; }
        float inv = 1.f / sum;
        for (int jj = 0; jj < T; ++jj) sc[jj] *= inv;
    }
    __syncthreads();
    if (tid < 16) {
        float acc = 0.f;
        for (int jj = 0; jj < T; ++jj) acc += sc[jj] * vc[((size_t)b*T + jj)*D_ + h*16 + tid];
        outc[(size_t)b*D_ + h*16 + tid] = acc * gam[layer*H_ + h];
    }
}

// ---------------- small helpers ----------------
__global__ __launch_bounds__(256) void bcast_ct_kernel(const float* __restrict__ ct, float* __restrict__ xc)
{
    int idx = blockIdx.x * 256 + threadIdx.x;
    xc[idx] = ct[idx & (D_ - 1)];
}

__global__ __launch_bounds__(256) void concat_kernel(
    const float* __restrict__ xc, const float* __restrict__ xp, float* __restrict__ xx)
{
    int idx = blockIdx.x * 256 + threadIdx.x;
    int d = idx & (D_ - 1);
    int r = idx >> 7;
    int b = r / (S_ + 1);
    int s = r % (S_ + 1);
    xx[idx] = (s == 0) ? xc[(size_t)b*D_ + d] : xp[((size_t)b*S_ + (s - 1))*D_ + d];
}

// ---------------- final head ----------------
__global__ __launch_bounds__(128) void head_kernel(
    const float* __restrict__ u, const float* __restrict__ fc_w, const float* __restrict__ fc_b,
    const float* __restrict__ fin_w, const float* __restrict__ fin_b, float* __restrict__ out)
{
    __shared__ float us[128], r0[128], r1[128];
    int b = blockIdx.x, tid = threadIdx.x;
    us[tid] = u[(size_t)b*D_ + tid];
    __syncthreads();
    float acc = fc_b[tid];
    for (int kk = 0; kk < 128; ++kk) acc += fc_w[tid*128 + kk] * us[kk];
    float rl = fmaxf(acc, 0.f);
    r0[tid] = fin_w[tid] * rl;
    r1[tid] = fin_w[128 + tid] * rl;
    __syncthreads();
    #pragma unroll
    for (int o = 64; o > 0; o >>= 1) {
        if (tid < o) { r0[tid] += r0[tid + o]; r1[tid] += r1[tid + o]; }
        __syncthreads();
    }
    if (tid == 0) {
        float l0 = r0[0] + fin_b[0], l1 = r1[0] + fin_b[1];
        float m = fmaxf(l0, l1);
        float e0 = __expf(l0 - m), e1 = __expf(l1 - m);
        float inv = 1.f / (e0 + e1);
        out[b*2 + 0] = e0 * inv;
        out[b*2 + 1] = e1 * inv;
    }
}

// ---------------- orchestration ----------------
extern "C" void kernel_launch(void* const* d_in, const int* in_sizes, int n_in,
                              void* d_out, int out_size, void* d_ws, size_t ws_size,
                              hipStream_t stream)
{
    (void)in_sizes; (void)n_in; (void)out_size;
    const float* x     = (const float*)d_in[0];
    const float* p4    = (const float*)d_in[1];
    const float* pe_w0 = (const float*)d_in[2];
    const float* pe_b0 = (const float*)d_in[3];
    const float* pe_w1 = (const float*)d_in[4];
    const float* pe_b1 = (const float*)d_in[5];
    const float* pe_w2 = (const float*)d_in[6];
    const float* pe_b2 = (const float*)d_in[7];
    const float* ie_w0 = (const float*)d_in[8];
    const float* ie_b0 = (const float*)d_in[9];
    const float* ie_w1 = (const float*)d_in[10];
    const float* ie_b1 = (const float*)d_in[11];
    const float* ie_w2 = (const float*)d_in[12];
    const float* ie_b2 = (const float*)d_in[13];
    const float* wq    = (const float*)d_in[14];
    const float* wk    = (const float*)d_in[15];
    const float* wv    = (const float*)d_in[16];
    const float* wo    = (const float*)d_in[17];
    const float* gam   = (const float*)d_in[18];
    const float* ln_g  = (const float*)d_in[19];
    const float* ln_b  = (const float*)d_in[20];
    const float* lnfc_g= (const float*)d_in[21];
    const float* lnfc_b= (const float*)d_in[22];
    const float* fc1_w = (const float*)d_in[23];
    const float* fc1_b = (const float*)d_in[24];
    const float* fc2_w = (const float*)d_in[25];
    const float* fc2_b = (const float*)d_in[26];
    const float* lam   = (const float*)d_in[27];
    const float* ct    = (const float*)d_in[28];
    const float* fc_w  = (const float*)d_in[29];
    const float* fc_b  = (const float*)d_in[30];
    const float* fin_w = (const float*)d_in[31];
    const float* fin_b = (const float*)d_in[32];

    float* ws = (float*)d_ws;
    const size_t o_bias = 0;
    const size_t o_prep = o_bias + 8388608;
    const size_t o_kpm  = o_prep + 49152;
    const size_t o_xp   = o_kpm  + 16384;
    const size_t o_b1   = o_xp   + 2097152;
    const size_t o_b2   = o_b1   + 2097152;
    const size_t o_b3   = o_b2   + 8388608;
    const size_t o_xx   = o_b3   + 2097152;
    const size_t o_xc   = o_xx   + 2113536;
    const size_t o_t1   = o_xc   + 16384;
    const size_t o_t2   = o_t1   + 16384;
    const size_t o_ac   = o_t2   + 65536;
    const size_t o_u    = o_ac   + 16384;
    const size_t o_end  = o_u    + 16384;

    size_t used_bytes = o_end * sizeof(float);
    if (used_bytes > ws_size) used_bytes = ws_size;
    hipMemsetAsync(d_ws, 0, used_bytes, stream);

    __hip_bfloat16* biasb = (__hip_bfloat16*)(ws + o_bias);
    float* prep = ws + o_prep;
    float* kpm  = ws + o_kpm;
    float* xp   = ws + o_xp;
    float* b1   = ws + o_b1;
    float* b2   = ws + o_b2;
    float* b3   = ws + o_b3;
    float* xx   = ws + o_xx;
    float* xc   = ws + o_xc;
    float* t2   = ws + o_t2;
    float* ac   = ws + o_ac;
    float* ufin = ws + o_u;

    const int NT = B_ * S_;        // 16384
    const int NC = B_ * (S_ + 1);  // 16512

    prep_kernel<<<NT/256, 256, 0, stream>>>(x, p4, prep, kpm);
    embed1_kernel<<<NT/2, 256, 0, stream>>>(x, pe_w0, pe_b0, b1);
    fc1_ln_kernel<<<NT/64, 256, 0, stream>>>(b1, nullptr, nullptr, pe_w1, pe_b1, nullptr, nullptr, b2);
    linmm_kernel<1,false><<<dim3(NT/64, 2), 256, 0, stream>>>(b2, pe_w2, pe_b2, xp, nullptr, nullptr, NT, 512, 128);
    bias_kernel<<<B_*33, 256, 0, stream>>>(p4, prep, ie_w0, ie_b0, ie_w1, ie_b1, ie_w2, ie_b2, biasb);

    float* qb = b2;
    float* kb = b2 + 2097152;
    float* vb = b2 + 4194304;

    // layer-0 LN (subsequent layers' LN fused into fc2_ln epilogue)
    ln_kernel<128><<<NT, 64, 0, stream>>>(xp, b1, ln_g, ln_b, nullptr);

    // ---- particle blocks ----
    for (int i = 0; i < 8; ++i) {
        const float* g1p = ln_g + (size_t)(i*3 + 1)*D_; const float* b1p = ln_b + (size_t)(i*3 + 1)*D_;
        const float* g2p = ln_g + (size_t)(i*3 + 2)*D_; const float* b2p = ln_b + (size_t)(i*3 + 2)*D_;

        qkvall_kernel<<<NT/64, 256, 0, stream>>>(
            b1, wq + (size_t)i*D_*D_, wk + (size_t)i*D_*D_, wv + (size_t)i*D_*D_, qb, kb, vb);
        attn_kernel<<<B_*H_, 256, 0, stream>>>(qb, kb, vb, biasb, kpm, gam, i, b1);
        wo_ln_kernel<<<NT/64, 256, 0, stream>>>(b1, wo + (size_t)i*D_*D_, g1p, b1p, xp, xp);
        fc1_ln_kernel<<<NT/64, 256, 0, stream>>>(xp, g2p, b2p,
            fc1_w + (size_t)i*F_*D_, fc1_b + (size_t)i*F_,
            lnfc_g + (size_t)i*F_, lnfc_b + (size_t)i*F_, b2);
        if (i < 7) {
            const float* gn = ln_g + (size_t)((i+1)*3 + 0)*D_;
            const float* bn = ln_b + (size_t)((i+1)*3 + 0)*D_;
            fc2_ln_kernel<true><<<NT/64, 256, 0, stream>>>(
                b2, fc2_w + (size_t)i*D_*F_, fc2_b + (size_t)i*D_, lam + (size_t)i*D_,
                xp, xp, gn, bn, b1);
        } else {
            fc2_ln_kernel<false><<<NT/64, 256, 0, stream>>>(
                b2, fc2_w + (size_t)i*D_*F_, fc2_b + (size_t)i*D_, lam + (size_t)i*D_,
                xp, xp, nullptr, nullptr, nullptr);
        }
    }

    // ---- class blocks ----
    bcast_ct_kernel<<<B_*D_/256, 256, 0, stream>>>(ct, xc);
    float* kc = b2;
    float* vc = b2 + 2113536;
    for (int i = 8; i < 10; ++i) {
        const float* g0p = ln_g + (size_t)(i*3 + 0)*D_; const float* b0p = ln_b + (size_t)(i*3 + 0)*D_;
        const float* g1p = ln_g + (size_t)(i*3 + 1)*D_; const float* b1p = ln_b + (size_t)(i*3 + 1)*D_;
        const float* g2p = ln_g + (size_t)(i*3 + 2)*D_; const float* b2p = ln_b + (size_t)(i*3 + 2)*D_;

        concat_kernel<<<(B_*(S_+1)*D_)/256, 256, 0, stream>>>(xc, xp, xx);
        ln_kernel<128><<<NC, 64, 0, stream>>>(xx, xx, g0p, b0p, nullptr);
        linmm_kernel<0,false><<<dim3(NC/64, 2), 256, 0, stream>>>(xx, wk + (size_t)i*D_*D_, nullptr, kc, nullptr, nullptr, NC, D_, D_);
        linmm_kernel<0,false><<<dim3(NC/64, 2), 256, 0, stream>>>(xx, wv + (size_t)i*D_*D_, nullptr, vc, nullptr, nullptr, NC, D_, D_);
        linmm_kernel<0,false><<<dim3(B_/64, 2), 256, 0, stream>>>(xc, wq + (size_t)i*D_*D_, nullptr, b3, nullptr, nullptr, B_, D_, D_);
        cattn_kernel<<<B_*H_, 256, 0, stream>>>(b3, kc, vc, kpm, gam, i, ac);
        wo_ln_kernel<<<B_/64, 256, 0, stream>>>(ac, wo + (size_t)i*D_*D_, g1p, b1p, xc, xc);
        fc1_ln_kernel<<<B_/64, 256, 0, stream>>>(xc, g2p, b2p,
            fc1_w + (size_t)i*F_*D_, fc1_b + (size_t)i*F_,
            lnfc_g + (size_t)i*F_, lnfc_b + (size_t)i*F_, t2);
        linmm_kernel<0,true><<<dim3(B_/64, 2), 256, 0, stream>>>(t2, fc2_w + (size_t)i*D_*F_, fc2_b + (size_t)i*D_, xc, xc, lam + (size_t)i*D_, B_, F_, D_);
    }

    // ---- head ----
    ln_kernel<128><<<B_, 64, 0, stream>>>(xc, ufin, nullptr, nullptr, nullptr);
    head_kernel<<<B_, 128, 0, stream>>>(ufin, fc_w, fc_b, fin_w, fin_b, (float*)d_out);
}

// Round 10
// 1304.490 us; speedup vs baseline: 1.0188x; 1.0188x over previous
//
#include <hip/hip_runtime.h>
#include <hip/hip_bf16.h>
#include <math.h>

// ---------------- constants ----------------
constexpr int B_  = 128;
constexpr int S_  = 128;
constexpr int FIN_= 16;
constexpr int D_  = 128;
constexpr int H_  = 8;
constexpr int F_  = 512;
constexpr float EPSF = 1e-5f;
constexpr float BN_SCALE_F = 0.99999500003749967f;  // 1/sqrt(1+1e-5)
constexpr float PI_F  = 3.14159265358979323846f;
constexpr float TWO_PI_F = 6.283185307179586477f;
constexpr float INV_TWO_PI_F = 0.15915494309189533577f;

using short8v = __attribute__((ext_vector_type(8))) short;
using float4v = __attribute__((ext_vector_type(4))) float;

__device__ __forceinline__ float gelu_f(float x) {
    return 0.5f * x * (1.0f + erff(x * 0.70710678118654752f));
}

// Abramowitz-Stegun 7.1.26 erf (|abs err| <= 1.5e-7); consumers bf16-quantize.
__device__ __forceinline__ float gelu_fast(float x) {
    float z = fabsf(x) * 0.70710678118654752f;
    float t = __builtin_amdgcn_rcpf(1.0f + 0.3275911f * z);
    float poly = t*(0.254829592f + t*(-0.284496736f + t*(1.421413741f + t*(-1.453152027f + t*1.061405429f))));
    float e = 1.0f - poly * __expf(-z*z);
    float s = (x >= 0.f) ? e : -e;
    return 0.5f * x * (1.0f + s);
}

__device__ __forceinline__ short f2b(float f) {
    union { __hip_bfloat16 h; short s; } u;
    u.h = __float2bfloat16(f);
    return u.s;
}

// ---------------- prep: pt/rap/phi + key-padding mask ----------------
__global__ __launch_bounds__(256) void prep_kernel(
    const float* __restrict__ x, const float* __restrict__ p4,
    float* __restrict__ prep, float* __restrict__ kpm)
{
    int idx = blockIdx.x * 256 + threadIdx.x;
    float px = p4[(size_t)idx*4 + 0];
    float py = p4[(size_t)idx*4 + 1];
    float pz = p4[(size_t)idx*4 + 2];
    float e  = p4[(size_t)idx*4 + 3];
    float pt = sqrtf(px*px + py*py);
    float den = fmaxf(e - pz, 1e-20f);
    float rap = 0.5f * log1pf(2.0f * pz / den);
    float phi = atan2f(py, px);
    prep[(size_t)idx*3 + 0] = pt;
    prep[(size_t)idx*3 + 1] = rap;
    prep[(size_t)idx*3 + 2] = phi;
    kpm[idx] = (x[(size_t)idx * FIN_] == 0.0f) ? 1.0f : 0.0f;
}

// ---------------- embed layer 1: LN16(x*BN) @ w0.T + b0, gelu ----------------
__global__ __launch_bounds__(256) void embed1_kernel(
    const float* __restrict__ x, const float* __restrict__ w0,
    const float* __restrict__ b0, float* __restrict__ e1)
{
    __shared__ float xs[2][16];
    __shared__ float ms[2], rss[2];
    int tid = threadIdx.x;
    int t0 = blockIdx.x * 2;
    if (tid < 32) {
        int t = tid >> 4, kk = tid & 15;
        xs[t][kk] = x[(size_t)(t0 + t) * FIN_ + kk] * BN_SCALE_F;
    }
    __syncthreads();
    if (tid < 2) {
        float s = 0.f;
        #pragma unroll
        for (int kk = 0; kk < 16; ++kk) s += xs[tid][kk];
        float m = s * (1.f/16.f);
        float vs = 0.f;
        #pragma unroll
        for (int kk = 0; kk < 16; ++kk) { float d = xs[tid][kk] - m; vs += d*d; }
        ms[tid] = m;
        rss[tid] = rsqrtf(vs * (1.f/16.f) + EPSF);
    }
    __syncthreads();
    int t = tid >> 7, o = tid & 127;
    float m = ms[t], r = rss[t];
    float acc = b0[o];
    #pragma unroll
    for (int kk = 0; kk < 16; ++kk)
        acc += w0[o*16 + kk] * ((xs[t][kk] - m) * r);
    e1[(size_t)(t0 + t)*128 + o] = gelu_f(acc);
}

// ---------------- generic MFMA linear (verified r2 template) ----------------
template<int ACT, bool HASRES>
__global__ __launch_bounds__(256) void linmm_kernel(
    const float* __restrict__ in, const float* __restrict__ w,
    const float* __restrict__ bias, float* __restrict__ out,
    const float* __restrict__ res, const float* __restrict__ lam,
    int N, int K, int Dout)
{
    __shared__ __align__(16) short As[64*64];
    __shared__ __align__(16) short Bs[64*64];
    int tid = threadIdx.x;
    int n0 = blockIdx.x * 64, o0 = blockIdx.y * 64;
    int lane = tid & 63, wv = tid >> 6;
    int srow = tid >> 2, scc = tid & 3;
    const float* ain = in + (size_t)(n0 + srow)*K + scc*16;
    const float* bin = w  + (size_t)(o0 + srow)*K + scc*16;
    float4v acc[4];
    #pragma unroll
    for (int n = 0; n < 4; ++n) acc[n] = (float4v){0.f,0.f,0.f,0.f};
    int c0 = scc * 2;
    int swz = srow & 7;
    int wrb = srow * 64;
    int arow = (wv << 4) + (lane & 15);
    int kgrp = lane >> 4;

    for (int k0 = 0; k0 < K; k0 += 64) {
        float4 a0 = *(const float4*)(ain + k0);
        float4 a1 = *(const float4*)(ain + k0 + 4);
        float4 a2 = *(const float4*)(ain + k0 + 8);
        float4 a3 = *(const float4*)(ain + k0 + 12);
        float4 g0 = *(const float4*)(bin + k0);
        float4 g1 = *(const float4*)(bin + k0 + 4);
        float4 g2 = *(const float4*)(bin + k0 + 8);
        float4 g3 = *(const float4*)(bin + k0 + 12);
        __syncthreads();
        short8v sa0, sa1, sb0, sb1;
        sa0[0]=f2b(a0.x); sa0[1]=f2b(a0.y); sa0[2]=f2b(a0.z); sa0[3]=f2b(a0.w);
        sa0[4]=f2b(a1.x); sa0[5]=f2b(a1.y); sa0[6]=f2b(a1.z); sa0[7]=f2b(a1.w);
        sa1[0]=f2b(a2.x); sa1[1]=f2b(a2.y); sa1[2]=f2b(a2.z); sa1[3]=f2b(a2.w);
        sa1[4]=f2b(a3.x); sa1[5]=f2b(a3.y); sa1[6]=f2b(a3.z); sa1[7]=f2b(a3.w);
        sb0[0]=f2b(g0.x); sb0[1]=f2b(g0.y); sb0[2]=f2b(g0.z); sb0[3]=f2b(g0.w);
        sb0[4]=f2b(g1.x); sb0[5]=f2b(g1.y); sb0[6]=f2b(g1.z); sb0[7]=f2b(g1.w);
        sb1[0]=f2b(g2.x); sb1[1]=f2b(g2.y); sb1[2]=f2b(g2.z); sb1[3]=f2b(g2.w);
        sb1[4]=f2b(g3.x); sb1[5]=f2b(g3.y); sb1[6]=f2b(g3.z); sb1[7]=f2b(g3.w);
        *(short8v*)&As[wrb + (((c0    ) ^ swz) << 3)] = sa0;
        *(short8v*)&As[wrb + (((c0 + 1) ^ swz) << 3)] = sa1;
        *(short8v*)&Bs[wrb + (((c0    ) ^ swz) << 3)] = sb0;
        *(short8v*)&Bs[wrb + (((c0 + 1) ^ swz) << 3)] = sb1;
        __syncthreads();
        #pragma unroll
        for (int ks = 0; ks < 2; ++ks) {
            int ch = (ks << 2) | kgrp;
            short8v av = *(short8v*)&As[arow*64 + ((ch ^ (arow & 7)) << 3)];
            #pragma unroll
            for (int n = 0; n < 4; ++n) {
                int brow = (n << 4) + (lane & 15);
                short8v bv = *(short8v*)&Bs[brow*64 + ((ch ^ (brow & 7)) << 3)];
                acc[n] = __builtin_amdgcn_mfma_f32_16x16x32_bf16(av, bv, acc[n], 0, 0, 0);
            }
        }
    }
    int colb = lane & 15, rgrp = lane >> 4;
    #pragma unroll
    for (int n = 0; n < 4; ++n) {
        int oo = o0 + (n << 4) + colb;
        float bvv = bias ? bias[oo] : 0.f;
        float lm = HASRES ? lam[oo] : 0.f;
        #pragma unroll
        for (int r = 0; r < 4; ++r) {
            int nn = n0 + (wv << 4) + (rgrp << 2) + r;
            float v = acc[n][r] + bvv;
            if (ACT == 1) v = gelu_f(v);
            if (HASRES) v += lm * res[(size_t)nn*Dout + oo];
            out[(size_t)nn*Dout + oo] = v;
        }
    }
}

// ---------------- QKV via wo_ln GEMM core (no LN), y selects weight ----------------
// grid (NT/64, 3). Block: 64 rows x full Dout=128, K=128.
__global__ __launch_bounds__(256) void qkvB_kernel(
    const float* __restrict__ in,
    const float* __restrict__ wq, const float* __restrict__ wk, const float* __restrict__ wv,
    float* __restrict__ qo, float* __restrict__ ko, float* __restrict__ vo)
{
    const float* w   = (blockIdx.y == 0) ? wq : (blockIdx.y == 1) ? wk : wv;
    float*       out = (blockIdx.y == 0) ? qo : (blockIdx.y == 1) ? ko : vo;
    __shared__ __align__(16) short As[64*128];
    __shared__ __align__(16) short Bs[128*128];
    int tid = threadIdx.x;
    int n0 = blockIdx.x * 64;

    {
        int srow = tid >> 2, scc = tid & 3;
        const float* ap = in + (size_t)(n0 + srow)*128 + scc*32;
        #pragma unroll
        for (int c = 0; c < 4; ++c) {
            float4 t0 = *(const float4*)(ap + c*8);
            float4 t1 = *(const float4*)(ap + c*8 + 4);
            short8v sv;
            sv[0]=f2b(t0.x); sv[1]=f2b(t0.y); sv[2]=f2b(t0.z); sv[3]=f2b(t0.w);
            sv[4]=f2b(t1.x); sv[5]=f2b(t1.y); sv[6]=f2b(t1.z); sv[7]=f2b(t1.w);
            int cc = scc*4 + c;
            *(short8v*)&As[srow*128 + ((cc ^ (srow & 7)) << 3)] = sv;
        }
    }
    {
        int brow = tid & 127, bh = tid >> 7;
        const float* bp = w + (size_t)brow*128 + bh*64;
        #pragma unroll
        for (int c = 0; c < 8; ++c) {
            float4 t0 = *(const float4*)(bp + c*8);
            float4 t1 = *(const float4*)(bp + c*8 + 4);
            short8v sv;
            sv[0]=f2b(t0.x); sv[1]=f2b(t0.y); sv[2]=f2b(t0.z); sv[3]=f2b(t0.w);
            sv[4]=f2b(t1.x); sv[5]=f2b(t1.y); sv[6]=f2b(t1.z); sv[7]=f2b(t1.w);
            int cc = bh*8 + c;
            *(short8v*)&Bs[brow*128 + ((cc ^ (brow & 7)) << 3)] = sv;
        }
    }
    __syncthreads();

    int lane = tid & 63, w4 = tid >> 6;
    int l15 = lane & 15, kgrp = lane >> 4;
    int rw = w4 >> 1, cw = w4 & 1;
    float4v acc[2][4];
    #pragma unroll
    for (int m = 0; m < 2; ++m)
        #pragma unroll
        for (int n = 0; n < 4; ++n) acc[m][n] = (float4v){0.f,0.f,0.f,0.f};
    #pragma unroll
    for (int ks = 0; ks < 4; ++ks) {
        int ch = ks*4 + kgrp;
        short8v av[2];
        #pragma unroll
        for (int m = 0; m < 2; ++m) {
            int arow = rw*32 + m*16 + l15;
            av[m] = *(short8v*)&As[arow*128 + ((ch ^ (arow & 7)) << 3)];
        }
        #pragma unroll
        for (int n = 0; n < 4; ++n) {
            int brow = cw*64 + n*16 + l15;
            short8v bv = *(short8v*)&Bs[brow*128 + ((ch ^ (brow & 7)) << 3)];
            #pragma unroll
            for (int m = 0; m < 2; ++m)
                acc[m][n] = __builtin_amdgcn_mfma_f32_16x16x32_bf16(av[m], bv, acc[m][n], 0, 0, 0);
        }
    }
    #pragma unroll
    for (int m = 0; m < 2; ++m) {
        #pragma unroll
        for (int r = 0; r < 4; ++r) {
            size_t row = (size_t)(n0 + rw*32 + m*16 + kgrp*4 + r);
            #pragma unroll
            for (int n = 0; n < 4; ++n) {
                int col = cw*64 + n*16 + l15;
                out[row*128 + col] = acc[m][n][r];
            }
        }
    }
}

// ---------------- fused WO gemm + LN + residual (proven r7) ----------------
__global__ __launch_bounds__(256) void wo_ln_kernel(
    const float* __restrict__ in, const float* __restrict__ w,
    const float* __restrict__ g, const float* __restrict__ bb,
    const float* __restrict__ res, float* __restrict__ out)
{
    __shared__ __align__(16) short As[64*128];
    __shared__ __align__(16) short Bs[128*128];
    __shared__ float gs[128], bs[128];
    __shared__ float parts[2][64][2];
    int tid = threadIdx.x;
    int n0 = blockIdx.x * 64;

    if (tid < 128) gs[tid] = g[tid];
    else bs[tid - 128] = bb[tid - 128];

    {
        int srow = tid >> 2, scc = tid & 3;
        const float* ap = in + (size_t)(n0 + srow)*128 + scc*32;
        #pragma unroll
        for (int c = 0; c < 4; ++c) {
            float4 t0 = *(const float4*)(ap + c*8);
            float4 t1 = *(const float4*)(ap + c*8 + 4);
            short8v sv;
            sv[0]=f2b(t0.x); sv[1]=f2b(t0.y); sv[2]=f2b(t0.z); sv[3]=f2b(t0.w);
            sv[4]=f2b(t1.x); sv[5]=f2b(t1.y); sv[6]=f2b(t1.z); sv[7]=f2b(t1.w);
            int cc = scc*4 + c;
            *(short8v*)&As[srow*128 + ((cc ^ (srow & 7)) << 3)] = sv;
        }
    }
    {
        int brow = tid & 127, bh = tid >> 7;
        const float* bp = w + (size_t)brow*128 + bh*64;
        #pragma unroll
        for (int c = 0; c < 8; ++c) {
            float4 t0 = *(const float4*)(bp + c*8);
            float4 t1 = *(const float4*)(bp + c*8 + 4);
            short8v sv;
            sv[0]=f2b(t0.x); sv[1]=f2b(t0.y); sv[2]=f2b(t0.z); sv[3]=f2b(t0.w);
            sv[4]=f2b(t1.x); sv[5]=f2b(t1.y); sv[6]=f2b(t1.z); sv[7]=f2b(t1.w);
            int cc = bh*8 + c;
            *(short8v*)&Bs[brow*128 + ((cc ^ (brow & 7)) << 3)] = sv;
        }
    }
    __syncthreads();

    int lane = tid & 63, w4 = tid >> 6;
    int l15 = lane & 15, kgrp = lane >> 4;
    int rw = w4 >> 1, cw = w4 & 1;
    float4v acc[2][4];
    #pragma unroll
    for (int m = 0; m < 2; ++m)
        #pragma unroll
        for (int n = 0; n < 4; ++n) acc[m][n] = (float4v){0.f,0.f,0.f,0.f};
    #pragma unroll
    for (int ks = 0; ks < 4; ++ks) {
        int ch = ks*4 + kgrp;
        short8v av[2];
        #pragma unroll
        for (int m = 0; m < 2; ++m) {
            int arow = rw*32 + m*16 + l15;
            av[m] = *(short8v*)&As[arow*128 + ((ch ^ (arow & 7)) << 3)];
        }
        #pragma unroll
        for (int n = 0; n < 4; ++n) {
            int brow = cw*64 + n*16 + l15;
            short8v bv = *(short8v*)&Bs[brow*128 + ((ch ^ (brow & 7)) << 3)];
            #pragma unroll
            for (int m = 0; m < 2; ++m)
                acc[m][n] = __builtin_amdgcn_mfma_f32_16x16x32_bf16(av[m], bv, acc[m][n], 0, 0, 0);
        }
    }
    #pragma unroll
    for (int m = 0; m < 2; ++m) {
        #pragma unroll
        for (int r = 0; r < 4; ++r) {
            float s = acc[m][0][r] + acc[m][1][r] + acc[m][2][r] + acc[m][3][r];
            float sq = acc[m][0][r]*acc[m][0][r] + acc[m][1][r]*acc[m][1][r]
                     + acc[m][2][r]*acc[m][2][r] + acc[m][3][r]*acc[m][3][r];
            s  += __shfl_xor(s, 1);  s  += __shfl_xor(s, 2);  s  += __shfl_xor(s, 4);  s  += __shfl_xor(s, 8);
            sq += __shfl_xor(sq, 1); sq += __shfl_xor(sq, 2); sq += __shfl_xor(sq, 4); sq += __shfl_xor(sq, 8);
            if (l15 == 0) {
                int rl = rw*32 + m*16 + kgrp*4 + r;
                parts[cw][rl][0] = s;
                parts[cw][rl][1] = sq;
            }
        }
    }
    __syncthreads();
    #pragma unroll
    for (int m = 0; m < 2; ++m) {
        int rl_base = rw*32 + m*16 + kgrp*4;
        #pragma unroll
        for (int r = 0; r < 4; ++r) {
            int rl = rl_base + r;
            float st = parts[0][rl][0] + parts[1][rl][0];
            float sqt = parts[0][rl][1] + parts[1][rl][1];
            float mean = st * (1.f/128.f);
            float var = sqt * (1.f/128.f) - mean*mean;
            float rs = rsqrtf(fmaxf(var, 0.f) + EPSF);
            size_t rowg = (size_t)(n0 + rl);
            #pragma unroll
            for (int n = 0; n < 4; ++n) {
                int col = cw*64 + n*16 + l15;
                float v = (acc[m][n][r] - mean) * rs * gs[col] + bs[col] + res[rowg*128 + col];
                out[rowg*128 + col] = v;
            }
        }
    }
}

// ---------------- fused LN-in + FC1 + GELU + LN512-out (proven r6) ----------------
__global__ __launch_bounds__(256) void fc1_ln_kernel(
    const float* __restrict__ in,
    const float* __restrict__ g, const float* __restrict__ bb,
    const float* __restrict__ w1, const float* __restrict__ b1,
    const float* __restrict__ lg, const float* __restrict__ lb,
    float* __restrict__ out)
{
    __shared__ __align__(16) short As[64*128];
    __shared__ __align__(16) short BUF[64*128];
    __shared__ float gs[128], bs[128];
    __shared__ float bs1[512], lgs[512], lbs[512];
    int tid = threadIdx.x;
    int n0 = blockIdx.x * 64;
    int srow = tid >> 2, scc = tid & 3;

    if (tid < 128) gs[tid] = g ? g[tid] : 1.f;
    else bs[tid - 128] = bb ? bb[tid - 128] : 0.f;
    for (int idx = tid; idx < 512; idx += 256) {
        bs1[idx] = b1[idx];
        lgs[idx] = lg ? lg[idx] : 1.f;
        lbs[idx] = lb ? lb[idx] : 0.f;
    }

    {   // A: LN staging (one-pass stats across 4 lanes/row)
        const float* ap = in + (size_t)(n0 + srow)*128 + scc*32;
        float vals[32];
        float s = 0.f, sq = 0.f;
        #pragma unroll
        for (int q8 = 0; q8 < 8; ++q8) {
            float4 t4 = *(const float4*)(ap + q8*4);
            vals[q8*4+0]=t4.x; vals[q8*4+1]=t4.y; vals[q8*4+2]=t4.z; vals[q8*4+3]=t4.w;
            s += t4.x + t4.y + t4.z + t4.w;
            sq += t4.x*t4.x + t4.y*t4.y + t4.z*t4.z + t4.w*t4.w;
        }
        s  += __shfl_xor(s, 1);  s  += __shfl_xor(s, 2);
        sq += __shfl_xor(sq, 1); sq += __shfl_xor(sq, 2);
        float mean = s * (1.f/128.f);
        float var = sq * (1.f/128.f) - mean*mean;
        float rs = rsqrtf(fmaxf(var, 0.f) + EPSF);
        __syncthreads();   // gs/bs visible
        #pragma unroll
        for (int c = 0; c < 4; ++c) {
            short8v sv;
            #pragma unroll
            for (int e = 0; e < 8; ++e) {
                int k = scc*32 + c*8 + e;
                sv[e] = f2b((vals[c*8+e] - mean) * rs * gs[k] + bs[k]);
            }
            int cc = scc*4 + c;
            *(short8v*)&As[srow*128 + ((cc ^ (srow & 7)) << 3)] = sv;
        }
    }
    __syncthreads();

    int lane = tid & 63, w4 = tid >> 6;
    int l15 = lane & 15, kgrp = lane >> 4;
    int arow = (w4 << 4) + l15;
    short8v aF[4];
    #pragma unroll
    for (int ks = 0; ks < 4; ++ks) {
        int ch = ks*4 + kgrp;
        aF[ks] = *(short8v*)&As[arow*128 + ((ch ^ (arow & 7)) << 3)];
    }
    float4v acc[32];
    #pragma unroll
    for (int n = 0; n < 32; ++n) acc[n] = (float4v){0.f,0.f,0.f,0.f};

    #pragma unroll
    for (int c8 = 0; c8 < 8; ++c8) {
        __syncthreads();
        {
            const float* bp = w1 + (size_t)(c8*64 + srow)*128 + scc*32;
            #pragma unroll
            for (int c = 0; c < 4; ++c) {
                float4 t0 = *(const float4*)(bp + c*8);
                float4 t1 = *(const float4*)(bp + c*8 + 4);
                short8v sv;
                sv[0]=f2b(t0.x); sv[1]=f2b(t0.y); sv[2]=f2b(t0.z); sv[3]=f2b(t0.w);
                sv[4]=f2b(t1.x); sv[5]=f2b(t1.y); sv[6]=f2b(t1.z); sv[7]=f2b(t1.w);
                int cc = scc*4 + c;
                *(short8v*)&BUF[srow*128 + ((cc ^ (srow & 7)) << 3)] = sv;
            }
        }
        __syncthreads();
        #pragma unroll
        for (int ks = 0; ks < 4; ++ks) {
            int ch = ks*4 + kgrp;
            #pragma unroll
            for (int n = 0; n < 4; ++n) {
                int brow = n*16 + l15;
                short8v bv = *(short8v*)&BUF[brow*128 + ((ch ^ (brow & 7)) << 3)];
                acc[c8*4+n] = __builtin_amdgcn_mfma_f32_16x16x32_bf16(aF[ks], bv, acc[c8*4+n], 0, 0, 0);
            }
        }
    }

    #pragma unroll
    for (int nf = 0; nf < 32; ++nf) {
        int col = nf*16 + l15;
        #pragma unroll
        for (int r = 0; r < 4; ++r)
            acc[nf][r] = gelu_f(acc[nf][r] + bs1[col]);
    }
    float mean[4], rsv[4];
    #pragma unroll
    for (int r = 0; r < 4; ++r) {
        float s = 0.f, sq = 0.f;
        #pragma unroll
        for (int nf = 0; nf < 32; ++nf) { float v = acc[nf][r]; s += v; sq += v*v; }
        s  += __shfl_xor(s, 1);  s  += __shfl_xor(s, 2);  s  += __shfl_xor(s, 4);  s  += __shfl_xor(s, 8);
        sq += __shfl_xor(sq, 1); sq += __shfl_xor(sq, 2); sq += __shfl_xor(sq, 4); sq += __shfl_xor(sq, 8);
        mean[r] = s * (1.f/512.f);
        float var = sq * (1.f/512.f) - mean[r]*mean[r];
        rsv[r] = rsqrtf(fmaxf(var, 0.f) + EPSF);
    }
    #pragma unroll
    for (int r = 0; r < 4; ++r) {
        size_t rowg = (size_t)(n0 + (w4 << 4) + (kgrp << 2) + r);
        #pragma unroll
        for (int nf = 0; nf < 32; ++nf) {
            int col = nf*16 + l15;
            out[rowg*512 + col] = (acc[nf][r] - mean[r]) * rsv[r] * lgs[col] + lbs[col];
        }
    }
}

// ---------------- interaction bias: dual-MFMA (proven r6) ----------------
__global__ __launch_bounds__(256) void bias_kernel(
    const float* __restrict__ p4, const float* __restrict__ prep,
    const float* __restrict__ w0, const float* __restrict__ b0,
    const float* __restrict__ w1, const float* __restrict__ b1,
    const float* __restrict__ w2, const float* __restrict__ b2,
    __hip_bfloat16* __restrict__ bias)
{
    __shared__ float pj[128][8];
    __shared__ float w0s[256], b0s[64], b1s[64], b2s[8];
    __shared__ __align__(16) short U[256*64];
    __shared__ __align__(16) short W1s[64*64];
    __shared__ __align__(16) short W2s[16*64];
    __shared__ short si[256], sj[256];
    int tid = threadIdx.x;
    int b  = blockIdx.x / 33;
    int p  = (blockIdx.x % 33) * 256 + tid;

    w0s[tid] = w0[tid];
    if (tid < 64) { b0s[tid] = b0[tid]; b1s[tid] = b1[tid]; }
    if (tid < 8)  b2s[tid] = b2[tid];
    {
        int o = tid >> 2;
        const float* wp = w1 + o*64 + (tid & 3) * 16;
        #pragma unroll
        for (int h2 = 0; h2 < 2; ++h2) {
            float4 t0 = *(const float4*)(wp + h2*8);
            float4 t1 = *(const float4*)(wp + h2*8 + 4);
            short8v sv;
            sv[0]=f2b(t0.x); sv[1]=f2b(t0.y); sv[2]=f2b(t0.z); sv[3]=f2b(t0.w);
            sv[4]=f2b(t1.x); sv[5]=f2b(t1.y); sv[6]=f2b(t1.z); sv[7]=f2b(t1.w);
            int cc = (tid & 3)*2 + h2;
            *(short8v*)&W1s[o*64 + ((cc ^ (o & 7)) << 3)] = sv;
        }
    }
    if (tid < 128) {
        int o2 = tid >> 3, c = tid & 7;
        short8v sv;
        #pragma unroll
        for (int e = 0; e < 8; ++e)
            sv[e] = (o2 < 8) ? f2b(w2[o2*64 + c*8 + e]) : (short)0;
        *(short8v*)&W2s[o2*64 + ((c ^ (o2 & 7)) << 3)] = sv;
    }
    if (tid < 128) {
        int s = tid;
        const float* pr = prep + ((size_t)b*S_ + s)*3;
        pj[s][0] = pr[0]; pj[s][1] = pr[1]; pj[s][2] = pr[2];
        const float* pp = p4 + ((size_t)b*S_ + s)*4;
        pj[s][3] = pp[0]; pj[s][4] = pp[1]; pj[s][5] = pp[2]; pj[s][6] = pp[3];
    }

    bool valid = p < 8256;
    int i = 0, j = 0;
    if (valid) {
        i = (int)((257.0f - sqrtf((float)(66049 - 8*p))) * 0.5f);
        if (i > 127) i = 127;
        if (i < 0) i = 0;
        while (i > 0 && i*(257 - i)/2 > p) --i;
        while ((i + 1)*(257 - (i + 1))/2 <= p) ++i;
        j = i + (p - i*(257 - i)/2);
    }
    si[tid] = (short)(valid ? i : -1);
    sj[tid] = (short)j;
    __syncthreads();

    float pti = pj[i][0], rapi = pj[i][1], phii = pj[i][2];
    float pxi = pj[i][3], pyi = pj[i][4], pzi = pj[i][5], ei = pj[i][6];
    float ptj = pj[j][0], rapj = pj[j][1], phij = pj[j][2];
    float pxj = pj[j][3], pyj = pj[j][4], pzj = pj[j][5], ej = pj[j][6];

    float dph = phij - phii + PI_F;
    dph = dph - floorf(dph * INV_TWO_PI_F) * TWO_PI_F;
    dph -= PI_F;
    float drap = rapi - rapj;
    float delta = fmaxf(sqrtf(drap*drap + dph*dph), 1e-8f);
    float ptmin = fminf(pti, ptj);
    float kt = fmaxf(ptmin * delta, 1e-8f);
    float z  = fmaxf(ptmin / fmaxf(pti + ptj, 1e-8f), 1e-8f);
    float es = ei + ej, pxs = pxi + pxj, pys = pyi + pyj, pzs = pzi + pzj;
    float m2 = fmaxf(es*es - pxs*pxs - pys*pys - pzs*pzs, 1e-8f);

    float f0 = logf(delta) * BN_SCALE_F;
    float f1 = logf(kt)    * BN_SCALE_F;
    float f2 = logf(z)     * BN_SCALE_F;
    float f3 = logf(m2)    * BN_SCALE_F;

    #pragma unroll
    for (int c8 = 0; c8 < 8; ++c8) {
        short8v sv;
        #pragma unroll
        for (int e = 0; e < 8; ++e) {
            int o = c8*8 + e;
            float a = b0s[o] + w0s[o*4+0]*f0 + w0s[o*4+1]*f1 + w0s[o*4+2]*f2 + w0s[o*4+3]*f3;
            sv[e] = f2b(gelu_fast(a * BN_SCALE_F));
        }
        *(short8v*)&U[tid*64 + ((c8 ^ (tid & 7)) << 3)] = sv;
    }
    __syncthreads();

    int lane = tid & 63, w4 = tid >> 6;
    int l15 = lane & 15, kgrp = lane >> 4;
    float4v acc[4][4];
    #pragma unroll
    for (int m = 0; m < 4; ++m)
        #pragma unroll
        for (int n = 0; n < 4; ++n) acc[m][n] = (float4v){0.f,0.f,0.f,0.f};
    #pragma unroll
    for (int ks = 0; ks < 2; ++ks) {
        int ch = ks*4 + kgrp;
        #pragma unroll
        for (int m = 0; m < 4; ++m) {
            int arow = w4*64 + m*16 + l15;
            short8v av = *(short8v*)&U[arow*64 + ((ch ^ (arow & 7)) << 3)];
            #pragma unroll
            for (int n = 0; n < 4; ++n) {
                int brow = n*16 + l15;
                short8v bv = *(short8v*)&W1s[brow*64 + ((ch ^ (brow & 7)) << 3)];
                acc[m][n] = __builtin_amdgcn_mfma_f32_16x16x32_bf16(av, bv, acc[m][n], 0, 0, 0);
            }
        }
    }

    #pragma unroll
    for (int m = 0; m < 4; ++m) {
        #pragma unroll
        for (int n = 0; n < 4; ++n) {
            int o = n*16 + l15;
            #pragma unroll
            for (int r = 0; r < 4; ++r) {
                int row = w4*64 + m*16 + kgrp*4 + r;
                float u2 = gelu_fast((acc[m][n][r] + b1s[o]) * BN_SCALE_F);
                U[row*64 + (((o >> 3) ^ (row & 7)) << 3) + (o & 7)] = f2b(u2);
            }
        }
    }

    float4v acc2[4];
    #pragma unroll
    for (int m = 0; m < 4; ++m) acc2[m] = (float4v){0.f,0.f,0.f,0.f};
    #pragma unroll
    for (int ks = 0; ks < 2; ++ks) {
        int ch = ks*4 + kgrp;
        short8v bv = *(short8v*)&W2s[l15*64 + ((ch ^ (l15 & 7)) << 3)];
        #pragma unroll
        for (int m = 0; m < 4; ++m) {
            int arow = w4*64 + m*16 + l15;
            short8v av = *(short8v*)&U[arow*64 + ((ch ^ (arow & 7)) << 3)];
            acc2[m] = __builtin_amdgcn_mfma_f32_16x16x32_bf16(av, bv, acc2[m], 0, 0, 0);
        }
    }

    size_t base = ((size_t)b*H_)*S_*S_;
    #pragma unroll
    for (int m = 0; m < 4; ++m) {
        #pragma unroll
        for (int r = 0; r < 4; ++r) {
            int row = w4*64 + m*16 + kgrp*4 + r;
            int ii = si[row], jj = sj[row];
            if (l15 < 8 && ii >= 0) {
                float v = gelu_fast((acc2[m][r] + b2s[l15]) * BN_SCALE_F);
                __hip_bfloat16 bv16 = __float2bfloat16(v);
                bias[base + (size_t)l15*S_*S_ + (size_t)ii*S_ + jj] = bv16;
                bias[base + (size_t)l15*S_*S_ + (size_t)jj*S_ + ii] = bv16;
            }
        }
    }
}

// ---------------- generic LayerNorm (64 threads/row) ----------------
template<int W>
__global__ __launch_bounds__(64) void ln_kernel(
    const float* __restrict__ in, float* __restrict__ out,
    const float* __restrict__ g, const float* __restrict__ bb,
    const float* __restrict__ res)
{
    constexpr int E = W / 64;
    int row = blockIdx.x;
    int lane = threadIdx.x;
    const float* r = in + (size_t)row * W;
    float vals[E];
    float s = 0.f;
    #pragma unroll
    for (int e = 0; e < E; ++e) { vals[e] = r[lane + 64*e]; s += vals[e]; }
    #pragma unroll
    for (int o = 32; o > 0; o >>= 1) s += __shfl_xor(s, o);
    float m = s * (1.f / W);
    float vsum = 0.f;
    #pragma unroll
    for (int e = 0; e < E; ++e) { float d = vals[e] - m; vsum += d*d; }
    #pragma unroll
    for (int o = 32; o > 0; o >>= 1) vsum += __shfl_xor(vsum, o);
    float rs = rsqrtf(vsum * (1.f / W) + EPSF);
    #pragma unroll
    for (int e = 0; e < E; ++e) {
        int c = lane + 64*e;
        float v = (vals[e] - m) * rs;
        if (g) v = v * g[c] + bb[c];
        if (res) v += res[(size_t)row*W + c];
        out[(size_t)row*W + c] = v;
    }
}

// ---------------- MFMA particle attention per (b,h) (proven r8) ----------------
__global__ __launch_bounds__(256) void attn_kernel(
    const float* __restrict__ q, const float* __restrict__ k, const float* __restrict__ v,
    const __hip_bfloat16* __restrict__ bias, const float* __restrict__ kpm,
    const float* __restrict__ gam, int layer, float* __restrict__ out)
{
    int bh = blockIdx.x;
    int b = bh >> 3, h = bh & 7;
    __shared__ __align__(16) short qs[128][40];
    __shared__ __align__(16) short ks[128][40];
    __shared__ __align__(16) short vst[16][136];
    __shared__ __align__(16) short pb[64][136];
    int tid = threadIdx.x;

    {
        int r = tid >> 1, hh = tid & 1;
        const float* qp = q + ((size_t)(b*S_ + r))*D_ + h*16 + hh*8;
        const float* kp = k + ((size_t)(b*S_ + r))*D_ + h*16 + hh*8;
        float4 a0 = *(const float4*)qp;
        float4 a1 = *(const float4*)(qp + 4);
        float4 c0 = *(const float4*)kp;
        float4 c1 = *(const float4*)(kp + 4);
        short8v sq, sk, zz;
        sq[0]=f2b(a0.x); sq[1]=f2b(a0.y); sq[2]=f2b(a0.z); sq[3]=f2b(a0.w);
        sq[4]=f2b(a1.x); sq[5]=f2b(a1.y); sq[6]=f2b(a1.z); sq[7]=f2b(a1.w);
        sk[0]=f2b(c0.x); sk[1]=f2b(c0.y); sk[2]=f2b(c0.z); sk[3]=f2b(c0.w);
        sk[4]=f2b(c1.x); sk[5]=f2b(c1.y); sk[6]=f2b(c1.z); sk[7]=f2b(c1.w);
        #pragma unroll
        for (int e = 0; e < 8; ++e) zz[e] = 0;
        *(short8v*)&qs[r][hh*8] = sq;
        *(short8v*)&ks[r][hh*8] = sk;
        *(short8v*)&qs[r][16 + hh*8] = zz;
        *(short8v*)&ks[r][16 + hh*8] = zz;
    }
    {
        int j = tid >> 1, dg = (tid & 1)*8;
        const float* vp = v + ((size_t)(b*S_ + j))*D_ + h*16 + dg;
        float4 v0 = *(const float4*)vp;
        float4 v1 = *(const float4*)(vp + 4);
        vst[dg+0][j] = f2b(v0.x); vst[dg+1][j] = f2b(v0.y);
        vst[dg+2][j] = f2b(v0.z); vst[dg+3][j] = f2b(v0.w);
        vst[dg+4][j] = f2b(v1.x); vst[dg+5][j] = f2b(v1.y);
        vst[dg+6][j] = f2b(v1.z); vst[dg+7][j] = f2b(v1.w);
    }
    float gm = gam[layer*H_ + h];
    __syncthreads();

    int lane = tid & 63, w = tid >> 6;
    int l15 = lane & 15, l4 = lane >> 4;

    float msk[8];
    #pragma unroll
    for (int n = 0; n < 8; ++n) msk[n] = kpm[b*S_ + n*16 + l15];

    #pragma unroll
    for (int half = 0; half < 2; ++half) {
        int mrow = half*64 + w*16;
        short8v aq = *(short8v*)&qs[mrow + l15][l4*8];
        float4v sf[8];
        #pragma unroll
        for (int n = 0; n < 8; ++n) {
            short8v bk = *(short8v*)&ks[n*16 + l15][l4*8];
            sf[n] = __builtin_amdgcn_mfma_f32_16x16x32_bf16(aq, bk, (float4v){0.f,0.f,0.f,0.f}, 0, 0, 0);
        }
        #pragma unroll
        for (int r = 0; r < 4; ++r) {
            int srow = mrow + l4*4 + r;
            const __hip_bfloat16* bp = bias + ((size_t)(b*H_ + h)*S_ + srow)*S_ + l15;
            float sc[8];
            float mx = -1e30f;
            #pragma unroll
            for (int n = 0; n < 8; ++n) {
                float s = sf[n][r]*0.25f + __bfloat162float(bp[n*16]);
                if (msk[n] != 0.f) s = -1e30f;
                sc[n] = s;
                mx = fmaxf(mx, s);
            }
            mx = fmaxf(mx, __shfl_xor(mx, 1));
            mx = fmaxf(mx, __shfl_xor(mx, 2));
            mx = fmaxf(mx, __shfl_xor(mx, 4));
            mx = fmaxf(mx, __shfl_xor(mx, 8));
            float sum = 0.f;
            #pragma unroll
            for (int n = 0; n < 8; ++n) { float e = __expf(sc[n] - mx); sc[n] = e; sum += e; }
            sum += __shfl_xor(sum, 1);
            sum += __shfl_xor(sum, 2);
            sum += __shfl_xor(sum, 4);
            sum += __shfl_xor(sum, 8);
            float inv = 1.f / sum;
            int lrow = w*16 + l4*4 + r;
            #pragma unroll
            for (int n = 0; n < 8; ++n)
                pb[lrow][n*16 + l15] = f2b(sc[n] * inv);
        }
        float4v of = (float4v){0.f,0.f,0.f,0.f};
        #pragma unroll
        for (int ks4 = 0; ks4 < 4; ++ks4) {
            short8v pa = *(short8v*)&pb[w*16 + l15][ks4*32 + l4*8];
            short8v vb = *(short8v*)&vst[l15][ks4*32 + l4*8];
            of = __builtin_amdgcn_mfma_f32_16x16x32_bf16(pa, vb, of, 0, 0, 0);
        }
        #pragma unroll
        for (int r = 0; r < 4; ++r)
            out[((size_t)(b*S_ + mrow + l4*4 + r))*D_ + h*16 + l15] = of[r] * gm;
    }
}

// ---------------- class-token attention ----------------
__global__ __launch_bounds__(256) void cattn_kernel(
    const float* __restrict__ qc, const float* __restrict__ kc, const float* __restrict__ vc,
    const float* __restrict__ kpm, const float* __restrict__ gam,
    int layer, float* __restrict__ outc)
{
    int b = blockIdx.x / H_, h = blockIdx.x % H_;
    __shared__ float sc[132];
    int tid = threadIdx.x;
    const int T = S_ + 1;
    if (tid < T) {
        float acc = 0.f;
        #pragma unroll
        for (int d = 0; d < 16; ++d)
            acc += qc[(size_t)b*D_ + h*16 + d] * kc[((size_t)b*T + tid)*D_ + h*16 + d];
        acc *= 0.25f;
        if (tid > 0 && kpm[b*S_ + tid - 1] != 0.f) acc = -1e30f;
        sc[tid] = acc;
    }
    __syncthreads();
    if (tid == 0) {
        float m = -1e30f;
        for (int jj = 0; jj < T; ++jj) m = fmaxf(m, sc[jj]);
        float sum = 0.f;
        for (int jj = 0; jj < T; ++jj) { float e = __expf(sc[jj] - m); sc[jj] = e; sum += e; }
        float inv = 1.f / sum;
        for (int jj = 0; jj < T; ++jj) sc[jj] *= inv;
    }
    __syncthreads();
    if (tid < 16) {
        float acc = 0.f;
        for (int jj = 0; jj < T; ++jj) acc += sc[jj] * vc[((size_t)b*T + jj)*D_ + h*16 + tid];
        outc[(size_t)b*D_ + h*16 + tid] = acc * gam[layer*H_ + h];
    }
}

// ---------------- small helpers ----------------
__global__ __launch_bounds__(256) void bcast_ct_kernel(const float* __restrict__ ct, float* __restrict__ xc)
{
    int idx = blockIdx.x * 256 + threadIdx.x;
    xc[idx] = ct[idx & (D_ - 1)];
}

__global__ __launch_bounds__(256) void concat_kernel(
    const float* __restrict__ xc, const float* __restrict__ xp, float* __restrict__ xx)
{
    int idx = blockIdx.x * 256 + threadIdx.x;
    int d = idx & (D_ - 1);
    int r = idx >> 7;
    int b = r / (S_ + 1);
    int s = r % (S_ + 1);
    xx[idx] = (s == 0) ? xc[(size_t)b*D_ + d] : xp[((size_t)b*S_ + (s - 1))*D_ + d];
}

// ---------------- final head ----------------
__global__ __launch_bounds__(128) void head_kernel(
    const float* __restrict__ u, const float* __restrict__ fc_w, const float* __restrict__ fc_b,
    const float* __restrict__ fin_w, const float* __restrict__ fin_b, float* __restrict__ out)
{
    __shared__ float us[128], r0[128], r1[128];
    int b = blockIdx.x, tid = threadIdx.x;
    us[tid] = u[(size_t)b*D_ + tid];
    __syncthreads();
    float acc = fc_b[tid];
    for (int kk = 0; kk < 128; ++kk) acc += fc_w[tid*128 + kk] * us[kk];
    float rl = fmaxf(acc, 0.f);
    r0[tid] = fin_w[tid] * rl;
    r1[tid] = fin_w[128 + tid] * rl;
    __syncthreads();
    #pragma unroll
    for (int o = 64; o > 0; o >>= 1) {
        if (tid < o) { r0[tid] += r0[tid + o]; r1[tid] += r1[tid + o]; }
        __syncthreads();
    }
    if (tid == 0) {
        float l0 = r0[0] + fin_b[0], l1 = r1[0] + fin_b[1];
        float m = fmaxf(l0, l1);
        float e0 = __expf(l0 - m), e1 = __expf(l1 - m);
        float inv = 1.f / (e0 + e1);
        out[b*2 + 0] = e0 * inv;
        out[b*2 + 1] = e1 * inv;
    }
}

// ---------------- orchestration ----------------
extern "C" void kernel_launch(void* const* d_in, const int* in_sizes, int n_in,
                              void* d_out, int out_size, void* d_ws, size_t ws_size,
                              hipStream_t stream)
{
    (void)in_sizes; (void)n_in; (void)out_size;
    const float* x     = (const float*)d_in[0];
    const float* p4    = (const float*)d_in[1];
    const float* pe_w0 = (const float*)d_in[2];
    const float* pe_b0 = (const float*)d_in[3];
    const float* pe_w1 = (const float*)d_in[4];
    const float* pe_b1 = (const float*)d_in[5];
    const float* pe_w2 = (const float*)d_in[6];
    const float* pe_b2 = (const float*)d_in[7];
    const float* ie_w0 = (const float*)d_in[8];
    const float* ie_b0 = (const float*)d_in[9];
    const float* ie_w1 = (const float*)d_in[10];
    const float* ie_b1 = (const float*)d_in[11];
    const float* ie_w2 = (const float*)d_in[12];
    const float* ie_b2 = (const float*)d_in[13];
    const float* wq    = (const float*)d_in[14];
    const float* wk    = (const float*)d_in[15];
    const float* wv    = (const float*)d_in[16];
    const float* wo    = (const float*)d_in[17];
    const float* gam   = (const float*)d_in[18];
    const float* ln_g  = (const float*)d_in[19];
    const float* ln_b  = (const float*)d_in[20];
    const float* lnfc_g= (const float*)d_in[21];
    const float* lnfc_b= (const float*)d_in[22];
    const float* fc1_w = (const float*)d_in[23];
    const float* fc1_b = (const float*)d_in[24];
    const float* fc2_w = (const float*)d_in[25];
    const float* fc2_b = (const float*)d_in[26];
    const float* lam   = (const float*)d_in[27];
    const float* ct    = (const float*)d_in[28];
    const float* fc_w  = (const float*)d_in[29];
    const float* fc_b  = (const float*)d_in[30];
    const float* fin_w = (const float*)d_in[31];
    const float* fin_b = (const float*)d_in[32];

    float* ws = (float*)d_ws;
    const size_t o_bias = 0;
    const size_t o_prep = o_bias + 8388608;
    const size_t o_kpm  = o_prep + 49152;
    const size_t o_xp   = o_kpm  + 16384;
    const size_t o_b1   = o_xp   + 2097152;
    const size_t o_b2   = o_b1   + 2097152;
    const size_t o_b3   = o_b2   + 8388608;
    const size_t o_xx   = o_b3   + 2097152;
    const size_t o_xc   = o_xx   + 2113536;
    const size_t o_t1   = o_xc   + 16384;
    const size_t o_t2   = o_t1   + 16384;
    const size_t o_ac   = o_t2   + 65536;
    const size_t o_u    = o_ac   + 16384;
    const size_t o_end  = o_u    + 16384;

    size_t used_bytes = o_end * sizeof(float);
    if (used_bytes > ws_size) used_bytes = ws_size;
    hipMemsetAsync(d_ws, 0, used_bytes, stream);

    __hip_bfloat16* biasb = (__hip_bfloat16*)(ws + o_bias);
    float* prep = ws + o_prep;
    float* kpm  = ws + o_kpm;
    float* xp   = ws + o_xp;
    float* b1   = ws + o_b1;
    float* b2   = ws + o_b2;
    float* b3   = ws + o_b3;
    float* xx   = ws + o_xx;
    float* xc   = ws + o_xc;
    float* t2   = ws + o_t2;
    float* ac   = ws + o_ac;
    float* ufin = ws + o_u;

    const int NT = B_ * S_;        // 16384
    const int NC = B_ * (S_ + 1);  // 16512

    prep_kernel<<<NT/256, 256, 0, stream>>>(x, p4, prep, kpm);
    embed1_kernel<<<NT/2, 256, 0, stream>>>(x, pe_w0, pe_b0, b1);
    fc1_ln_kernel<<<NT/64, 256, 0, stream>>>(b1, nullptr, nullptr, pe_w1, pe_b1, nullptr, nullptr, b2);
    linmm_kernel<1,false><<<dim3(NT/64, 2), 256, 0, stream>>>(b2, pe_w2, pe_b2, xp, nullptr, nullptr, NT, 512, 128);
    bias_kernel<<<B_*33, 256, 0, stream>>>(p4, prep, ie_w0, ie_b0, ie_w1, ie_b1, ie_w2, ie_b2, biasb);

    float* qb = b2;
    float* kb = b2 + 2097152;
    float* vb = b2 + 4194304;

    // ---- particle blocks (r8 structure; qkvB replaces qkv3) ----
    for (int i = 0; i < 8; ++i) {
        const float* g0p = ln_g + (size_t)(i*3 + 0)*D_; const float* b0p = ln_b + (size_t)(i*3 + 0)*D_;
        const float* g1p = ln_g + (size_t)(i*3 + 1)*D_; const float* b1p = ln_b + (size_t)(i*3 + 1)*D_;
        const float* g2p = ln_g + (size_t)(i*3 + 2)*D_; const float* b2p = ln_b + (size_t)(i*3 + 2)*D_;

        ln_kernel<128><<<NT, 64, 0, stream>>>(xp, b1, g0p, b0p, nullptr);
        qkvB_kernel<<<dim3(NT/64, 3), 256, 0, stream>>>(
            b1, wq + (size_t)i*D_*D_, wk + (size_t)i*D_*D_, wv + (size_t)i*D_*D_, qb, kb, vb);
        attn_kernel<<<B_*H_, 256, 0, stream>>>(qb, kb, vb, biasb, kpm, gam, i, b1);
        wo_ln_kernel<<<NT/64, 256, 0, stream>>>(b1, wo + (size_t)i*D_*D_, g1p, b1p, xp, xp);
        fc1_ln_kernel<<<NT/64, 256, 0, stream>>>(xp, g2p, b2p,
            fc1_w + (size_t)i*F_*D_, fc1_b + (size_t)i*F_,
            lnfc_g + (size_t)i*F_, lnfc_b + (size_t)i*F_, b2);
        linmm_kernel<0,true><<<dim3(NT/64, 2), 256, 0, stream>>>(b2, fc2_w + (size_t)i*D_*F_, fc2_b + (size_t)i*D_, xp, xp, lam + (size_t)i*D_, NT, F_, D_);
    }

    // ---- class blocks ----
    bcast_ct_kernel<<<B_*D_/256, 256, 0, stream>>>(ct, xc);
    float* kc = b2;
    float* vc = b2 + 2113536;
    for (int i = 8; i < 10; ++i) {
        const float* g0p = ln_g + (size_t)(i*3 + 0)*D_; const float* b0p = ln_b + (size_t)(i*3 + 0)*D_;
        const float* g1p = ln_g + (size_t)(i*3 + 1)*D_; const float* b1p = ln_b + (size_t)(i*3 + 1)*D_;
        const float* g2p = ln_g + (size_t)(i*3 + 2)*D_; const float* b2p = ln_b + (size_t)(i*3 + 2)*D_;

        concat_kernel<<<(B_*(S_+1)*D_)/256, 256, 0, stream>>>(xc, xp, xx);
        ln_kernel<128><<<NC, 64, 0, stream>>>(xx, xx, g0p, b0p, nullptr);
        linmm_kernel<0,false><<<dim3(NC/64, 2), 256, 0, stream>>>(xx, wk + (size_t)i*D_*D_, nullptr, kc, nullptr, nullptr, NC, D_, D_);
        linmm_kernel<0,false><<<dim3(NC/64, 2), 256, 0, stream>>>(xx, wv + (size_t)i*D_*D_, nullptr, vc, nullptr, nullptr, NC, D_, D_);
        linmm_kernel<0,false><<<dim3(B_/64, 2), 256, 0, stream>>>(xc, wq + (size_t)i*D_*D_, nullptr, b3, nullptr, nullptr, B_, D_, D_);
        cattn_kernel<<<B_*H_, 256, 0, stream>>>(b3, kc, vc, kpm, gam, i, ac);
        linmm_kernel<0,false><<<dim3(B_/64, 2), 256, 0, stream>>>(ac, wo + (size_t)i*D_*D_, nullptr, b3, nullptr, nullptr, B_, D_, D_);
        ln_kernel<128><<<B_, 64, 0, stream>>>(b3, xc, g1p, b1p, xc);
        fc1_ln_kernel<<<B_/64, 256, 0, stream>>>(xc, g2p, b2p,
            fc1_w + (size_t)i*F_*D_, fc1_b + (size_t)i*F_,
            lnfc_g + (size_t)i*F_, lnfc_b + (size_t)i*F_, t2);
        linmm_kernel<0,true><<<dim3(B_/64, 2), 256, 0, stream>>>(t2, fc2_w + (size_t)i*D_*F_, fc2_b + (size_t)i*D_, xc, xc, lam + (size_t)i*D_, B_, F_, D_);
    }

    // ---- head ----
    ln_kernel<128><<<B_, 64, 0, stream>>>(xc, ufin, nullptr, nullptr, nullptr);
    head_kernel<<<B_, 128, 0, stream>>>(ufin, fc_w, fc_b, fin_w, fin_b, (float*)d_out);
}

// Round 12
// 1271.970 us; speedup vs baseline: 1.0449x; 1.0256x over previous
//
#include <hip/hip_runtime.h>
#include <hip/hip_bf16.h>
#include <math.h>

// ---------------- constants ----------------
constexpr int B_  = 128;
constexpr int S_  = 128;
constexpr int FIN_= 16;
constexpr int D_  = 128;
constexpr int H_  = 8;
constexpr int F_  = 512;
constexpr float EPSF = 1e-5f;
constexpr float BN_SCALE_F = 0.99999500003749967f;  // 1/sqrt(1+1e-5)
constexpr float PI_F  = 3.14159265358979323846f;
constexpr float TWO_PI_F = 6.283185307179586477f;
constexpr float INV_TWO_PI_F = 0.15915494309189533577f;

using short8v = __attribute__((ext_vector_type(8))) short;
using float4v = __attribute__((ext_vector_type(4))) float;

__device__ __forceinline__ float gelu_f(float x) {
    return 0.5f * x * (1.0f + erff(x * 0.70710678118654752f));
}

// Abramowitz-Stegun 7.1.26 erf (|abs err| <= 1.5e-7); consumers bf16-quantize.
__device__ __forceinline__ float gelu_fast(float x) {
    float z = fabsf(x) * 0.70710678118654752f;
    float t = __builtin_amdgcn_rcpf(1.0f + 0.3275911f * z);
    float poly = t*(0.254829592f + t*(-0.284496736f + t*(1.421413741f + t*(-1.453152027f + t*1.061405429f))));
    float e = 1.0f - poly * __expf(-z*z);
    float s = (x >= 0.f) ? e : -e;
    return 0.5f * x * (1.0f + s);
}

__device__ __forceinline__ short f2b(float f) {
    union { __hip_bfloat16 h; short s; } u;
    u.h = __float2bfloat16(f);
    return u.s;
}

// ---------------- prep: pt/rap/phi + key-padding mask ----------------
__global__ __launch_bounds__(256) void prep_kernel(
    const float* __restrict__ x, const float* __restrict__ p4,
    float* __restrict__ prep, float* __restrict__ kpm)
{
    int idx = blockIdx.x * 256 + threadIdx.x;
    float px = p4[(size_t)idx*4 + 0];
    float py = p4[(size_t)idx*4 + 1];
    float pz = p4[(size_t)idx*4 + 2];
    float e  = p4[(size_t)idx*4 + 3];
    float pt = sqrtf(px*px + py*py);
    float den = fmaxf(e - pz, 1e-20f);
    float rap = 0.5f * log1pf(2.0f * pz / den);
    float phi = atan2f(py, px);
    prep[(size_t)idx*3 + 0] = pt;
    prep[(size_t)idx*3 + 1] = rap;
    prep[(size_t)idx*3 + 2] = phi;
    kpm[idx] = (x[(size_t)idx * FIN_] == 0.0f) ? 1.0f : 0.0f;
}

// ---------------- embed layer 1: LN16(x*BN) @ w0.T + b0, gelu ----------------
__global__ __launch_bounds__(256) void embed1_kernel(
    const float* __restrict__ x, const float* __restrict__ w0,
    const float* __restrict__ b0, float* __restrict__ e1)
{
    __shared__ float xs[2][16];
    __shared__ float ms[2], rss[2];
    int tid = threadIdx.x;
    int t0 = blockIdx.x * 2;
    if (tid < 32) {
        int t = tid >> 4, kk = tid & 15;
        xs[t][kk] = x[(size_t)(t0 + t) * FIN_ + kk] * BN_SCALE_F;
    }
    __syncthreads();
    if (tid < 2) {
        float s = 0.f;
        #pragma unroll
        for (int kk = 0; kk < 16; ++kk) s += xs[tid][kk];
        float m = s * (1.f/16.f);
        float vs = 0.f;
        #pragma unroll
        for (int kk = 0; kk < 16; ++kk) { float d = xs[tid][kk] - m; vs += d*d; }
        ms[tid] = m;
        rss[tid] = rsqrtf(vs * (1.f/16.f) + EPSF);
    }
    __syncthreads();
    int t = tid >> 7, o = tid & 127;
    float m = ms[t], r = rss[t];
    float acc = b0[o];
    #pragma unroll
    for (int kk = 0; kk < 16; ++kk)
        acc += w0[o*16 + kk] * ((xs[t][kk] - m) * r);
    e1[(size_t)(t0 + t)*128 + o] = gelu_f(acc);
}

// ---------------- generic MFMA linear (verified r2 template) ----------------
template<int ACT, bool HASRES>
__global__ __launch_bounds__(256) void linmm_kernel(
    const float* __restrict__ in, const float* __restrict__ w,
    const float* __restrict__ bias, float* __restrict__ out,
    const float* __restrict__ res, const float* __restrict__ lam,
    int N, int K, int Dout)
{
    __shared__ __align__(16) short As[64*64];
    __shared__ __align__(16) short Bs[64*64];
    int tid = threadIdx.x;
    int n0 = blockIdx.x * 64, o0 = blockIdx.y * 64;
    int lane = tid & 63, wv = tid >> 6;
    int srow = tid >> 2, scc = tid & 3;
    const float* ain = in + (size_t)(n0 + srow)*K + scc*16;
    const float* bin = w  + (size_t)(o0 + srow)*K + scc*16;
    float4v acc[4];
    #pragma unroll
    for (int n = 0; n < 4; ++n) acc[n] = (float4v){0.f,0.f,0.f,0.f};
    int c0 = scc * 2;
    int swz = srow & 7;
    int wrb = srow * 64;
    int arow = (wv << 4) + (lane & 15);
    int kgrp = lane >> 4;

    for (int k0 = 0; k0 < K; k0 += 64) {
        float4 a0 = *(const float4*)(ain + k0);
        float4 a1 = *(const float4*)(ain + k0 + 4);
        float4 a2 = *(const float4*)(ain + k0 + 8);
        float4 a3 = *(const float4*)(ain + k0 + 12);
        float4 g0 = *(const float4*)(bin + k0);
        float4 g1 = *(const float4*)(bin + k0 + 4);
        float4 g2 = *(const float4*)(bin + k0 + 8);
        float4 g3 = *(const float4*)(bin + k0 + 12);
        __syncthreads();
        short8v sa0, sa1, sb0, sb1;
        sa0[0]=f2b(a0.x); sa0[1]=f2b(a0.y); sa0[2]=f2b(a0.z); sa0[3]=f2b(a0.w);
        sa0[4]=f2b(a1.x); sa0[5]=f2b(a1.y); sa0[6]=f2b(a1.z); sa0[7]=f2b(a1.w);
        sa1[0]=f2b(a2.x); sa1[1]=f2b(a2.y); sa1[2]=f2b(a2.z); sa1[3]=f2b(a2.w);
        sa1[4]=f2b(a3.x); sa1[5]=f2b(a3.y); sa1[6]=f2b(a3.z); sa1[7]=f2b(a3.w);
        sb0[0]=f2b(g0.x); sb0[1]=f2b(g0.y); sb0[2]=f2b(g0.z); sb0[3]=f2b(g0.w);
        sb0[4]=f2b(g1.x); sb0[5]=f2b(g1.y); sb0[6]=f2b(g1.z); sb0[7]=f2b(g1.w);
        sb1[0]=f2b(g2.x); sb1[1]=f2b(g2.y); sb1[2]=f2b(g2.z); sb1[3]=f2b(g2.w);
        sb1[4]=f2b(g3.x); sb1[5]=f2b(g3.y); sb1[6]=f2b(g3.z); sb1[7]=f2b(g3.w);
        *(short8v*)&As[wrb + (((c0    ) ^ swz) << 3)] = sa0;
        *(short8v*)&As[wrb + (((c0 + 1) ^ swz) << 3)] = sa1;
        *(short8v*)&Bs[wrb + (((c0    ) ^ swz) << 3)] = sb0;
        *(short8v*)&Bs[wrb + (((c0 + 1) ^ swz) << 3)] = sb1;
        __syncthreads();
        #pragma unroll
        for (int ks = 0; ks < 2; ++ks) {
            int ch = (ks << 2) | kgrp;
            short8v av = *(short8v*)&As[arow*64 + ((ch ^ (arow & 7)) << 3)];
            #pragma unroll
            for (int n = 0; n < 4; ++n) {
                int brow = (n << 4) + (lane & 15);
                short8v bv = *(short8v*)&Bs[brow*64 + ((ch ^ (brow & 7)) << 3)];
                acc[n] = __builtin_amdgcn_mfma_f32_16x16x32_bf16(av, bv, acc[n], 0, 0, 0);
            }
        }
    }
    int colb = lane & 15, rgrp = lane >> 4;
    #pragma unroll
    for (int n = 0; n < 4; ++n) {
        int oo = o0 + (n << 4) + colb;
        float bvv = bias ? bias[oo] : 0.f;
        float lm = HASRES ? lam[oo] : 0.f;
        #pragma unroll
        for (int r = 0; r < 4; ++r) {
            int nn = n0 + (wv << 4) + (rgrp << 2) + r;
            float v = acc[n][r] + bvv;
            if (ACT == 1) v = gelu_f(v);
            if (HASRES) v += lm * res[(size_t)nn*Dout + oo];
            out[(size_t)nn*Dout + oo] = v;
        }
    }
}

// ---------------- QKV batched linmm (verbatim body, z selects weight/out) ----------------
__global__ __launch_bounds__(256) void qkv3_kernel(
    const float* __restrict__ in,
    const float* __restrict__ wq, const float* __restrict__ wk, const float* __restrict__ wv,
    float* __restrict__ qo, float* __restrict__ ko, float* __restrict__ vo)
{
    const float* w   = (blockIdx.z == 0) ? wq : (blockIdx.z == 1) ? wk : wv;
    float*       out = (blockIdx.z == 0) ? qo : (blockIdx.z == 1) ? ko : vo;
    const int K = 128, Dout = 128;
    __shared__ __align__(16) short As[64*64];
    __shared__ __align__(16) short Bs[64*64];
    int tid = threadIdx.x;
    int n0 = blockIdx.x * 64, o0 = blockIdx.y * 64;
    int lane = tid & 63, wvv = tid >> 6;
    int srow = tid >> 2, scc = tid & 3;
    const float* ain = in + (size_t)(n0 + srow)*K + scc*16;
    const float* bin = w  + (size_t)(o0 + srow)*K + scc*16;
    float4v acc[4];
    #pragma unroll
    for (int n = 0; n < 4; ++n) acc[n] = (float4v){0.f,0.f,0.f,0.f};
    int c0 = scc * 2;
    int swz = srow & 7;
    int wrb = srow * 64;
    int arow = (wvv << 4) + (lane & 15);
    int kgrp = lane >> 4;

    for (int k0 = 0; k0 < K; k0 += 64) {
        float4 a0 = *(const float4*)(ain + k0);
        float4 a1 = *(const float4*)(ain + k0 + 4);
        float4 a2 = *(const float4*)(ain + k0 + 8);
        float4 a3 = *(const float4*)(ain + k0 + 12);
        float4 g0 = *(const float4*)(bin + k0);
        float4 g1 = *(const float4*)(bin + k0 + 4);
        float4 g2 = *(const float4*)(bin + k0 + 8);
        float4 g3 = *(const float4*)(bin + k0 + 12);
        __syncthreads();
        short8v sa0, sa1, sb0, sb1;
        sa0[0]=f2b(a0.x); sa0[1]=f2b(a0.y); sa0[2]=f2b(a0.z); sa0[3]=f2b(a0.w);
        sa0[4]=f2b(a1.x); sa0[5]=f2b(a1.y); sa0[6]=f2b(a1.z); sa0[7]=f2b(a1.w);
        sa1[0]=f2b(a2.x); sa1[1]=f2b(a2.y); sa1[2]=f2b(a2.z); sa1[3]=f2b(a2.w);
        sa1[4]=f2b(a3.x); sa1[5]=f2b(a3.y); sa1[6]=f2b(a3.z); sa1[7]=f2b(a3.w);
        sb0[0]=f2b(g0.x); sb0[1]=f2b(g0.y); sb0[2]=f2b(g0.z); sb0[3]=f2b(g0.w);
        sb0[4]=f2b(g1.x); sb0[5]=f2b(g1.y); sb0[6]=f2b(g1.z); sb0[7]=f2b(g1.w);
        sb1[0]=f2b(g2.x); sb1[1]=f2b(g2.y); sb1[2]=f2b(g2.z); sb1[3]=f2b(g2.w);
        sb1[4]=f2b(g3.x); sb1[5]=f2b(g3.y); sb1[6]=f2b(g3.z); sb1[7]=f2b(g3.w);
        *(short8v*)&As[wrb + (((c0    ) ^ swz) << 3)] = sa0;
        *(short8v*)&As[wrb + (((c0 + 1) ^ swz) << 3)] = sa1;
        *(short8v*)&Bs[wrb + (((c0    ) ^ swz) << 3)] = sb0;
        *(short8v*)&Bs[wrb + (((c0 + 1) ^ swz) << 3)] = sb1;
        __syncthreads();
        #pragma unroll
        for (int ks = 0; ks < 2; ++ks) {
            int ch = (ks << 2) | kgrp;
            short8v av = *(short8v*)&As[arow*64 + ((ch ^ (arow & 7)) << 3)];
            #pragma unroll
            for (int n = 0; n < 4; ++n) {
                int brow = (n << 4) + (lane & 15);
                short8v bv = *(short8v*)&Bs[brow*64 + ((ch ^ (brow & 7)) << 3)];
                acc[n] = __builtin_amdgcn_mfma_f32_16x16x32_bf16(av, bv, acc[n], 0, 0, 0);
            }
        }
    }
    int colb = lane & 15, rgrp = lane >> 4;
    #pragma unroll
    for (int n = 0; n < 4; ++n) {
        int oo = o0 + (n << 4) + colb;
        #pragma unroll
        for (int r = 0; r < 4; ++r) {
            int nn = n0 + (wvv << 4) + (rgrp << 2) + r;
            out[(size_t)nn*Dout + oo] = acc[n][r];
        }
    }
}

// ---------------- fused WO gemm + LN + residual (proven r7) ----------------
__global__ __launch_bounds__(256) void wo_ln_kernel(
    const float* __restrict__ in, const float* __restrict__ w,
    const float* __restrict__ g, const float* __restrict__ bb,
    const float* __restrict__ res, float* __restrict__ out)
{
    __shared__ __align__(16) short As[64*128];
    __shared__ __align__(16) short Bs[128*128];
    __shared__ float gs[128], bs[128];
    __shared__ float parts[2][64][2];
    int tid = threadIdx.x;
    int n0 = blockIdx.x * 64;

    if (tid < 128) gs[tid] = g[tid];
    else bs[tid - 128] = bb[tid - 128];

    {
        int srow = tid >> 2, scc = tid & 3;
        const float* ap = in + (size_t)(n0 + srow)*128 + scc*32;
        #pragma unroll
        for (int c = 0; c < 4; ++c) {
            float4 t0 = *(const float4*)(ap + c*8);
            float4 t1 = *(const float4*)(ap + c*8 + 4);
            short8v sv;
            sv[0]=f2b(t0.x); sv[1]=f2b(t0.y); sv[2]=f2b(t0.z); sv[3]=f2b(t0.w);
            sv[4]=f2b(t1.x); sv[5]=f2b(t1.y); sv[6]=f2b(t1.z); sv[7]=f2b(t1.w);
            int cc = scc*4 + c;
            *(short8v*)&As[srow*128 + ((cc ^ (srow & 7)) << 3)] = sv;
        }
    }
    {
        int brow = tid & 127, bh = tid >> 7;
        const float* bp = w + (size_t)brow*128 + bh*64;
        #pragma unroll
        for (int c = 0; c < 8; ++c) {
            float4 t0 = *(const float4*)(bp + c*8);
            float4 t1 = *(const float4*)(bp + c*8 + 4);
            short8v sv;
            sv[0]=f2b(t0.x); sv[1]=f2b(t0.y); sv[2]=f2b(t0.z); sv[3]=f2b(t0.w);
            sv[4]=f2b(t1.x); sv[5]=f2b(t1.y); sv[6]=f2b(t1.z); sv[7]=f2b(t1.w);
            int cc = bh*8 + c;
            *(short8v*)&Bs[brow*128 + ((cc ^ (brow & 7)) << 3)] = sv;
        }
    }
    __syncthreads();

    int lane = tid & 63, w4 = tid >> 6;
    int l15 = lane & 15, kgrp = lane >> 4;
    int rw = w4 >> 1, cw = w4 & 1;
    float4v acc[2][4];
    #pragma unroll
    for (int m = 0; m < 2; ++m)
        #pragma unroll
        for (int n = 0; n < 4; ++n) acc[m][n] = (float4v){0.f,0.f,0.f,0.f};
    #pragma unroll
    for (int ks = 0; ks < 4; ++ks) {
        int ch = ks*4 + kgrp;
        short8v av[2];
        #pragma unroll
        for (int m = 0; m < 2; ++m) {
            int arow = rw*32 + m*16 + l15;
            av[m] = *(short8v*)&As[arow*128 + ((ch ^ (arow & 7)) << 3)];
        }
        #pragma unroll
        for (int n = 0; n < 4; ++n) {
            int brow = cw*64 + n*16 + l15;
            short8v bv = *(short8v*)&Bs[brow*128 + ((ch ^ (brow & 7)) << 3)];
            #pragma unroll
            for (int m = 0; m < 2; ++m)
                acc[m][n] = __builtin_amdgcn_mfma_f32_16x16x32_bf16(av[m], bv, acc[m][n], 0, 0, 0);
        }
    }
    #pragma unroll
    for (int m = 0; m < 2; ++m) {
        #pragma unroll
        for (int r = 0; r < 4; ++r) {
            float s = acc[m][0][r] + acc[m][1][r] + acc[m][2][r] + acc[m][3][r];
            float sq = acc[m][0][r]*acc[m][0][r] + acc[m][1][r]*acc[m][1][r]
                     + acc[m][2][r]*acc[m][2][r] + acc[m][3][r]*acc[m][3][r];
            s  += __shfl_xor(s, 1);  s  += __shfl_xor(s, 2);  s  += __shfl_xor(s, 4);  s  += __shfl_xor(s, 8);
            sq += __shfl_xor(sq, 1); sq += __shfl_xor(sq, 2); sq += __shfl_xor(sq, 4); sq += __shfl_xor(sq, 8);
            if (l15 == 0) {
                int rl = rw*32 + m*16 + kgrp*4 + r;
                parts[cw][rl][0] = s;
                parts[cw][rl][1] = sq;
            }
        }
    }
    __syncthreads();
    #pragma unroll
    for (int m = 0; m < 2; ++m) {
        int rl_base = rw*32 + m*16 + kgrp*4;
        #pragma unroll
        for (int r = 0; r < 4; ++r) {
            int rl = rl_base + r;
            float st = parts[0][rl][0] + parts[1][rl][0];
            float sqt = parts[0][rl][1] + parts[1][rl][1];
            float mean = st * (1.f/128.f);
            float var = sqt * (1.f/128.f) - mean*mean;
            float rs = rsqrtf(fmaxf(var, 0.f) + EPSF);
            size_t rowg = (size_t)(n0 + rl);
            #pragma unroll
            for (int n = 0; n < 4; ++n) {
                int col = cw*64 + n*16 + l15;
                float v = (acc[m][n][r] - mean) * rs * gs[col] + bs[col] + res[rowg*128 + col];
                out[rowg*128 + col] = v;
            }
        }
    }
}

// ---------------- fused LN-in + FC1 + GELU + LN512-out (proven r6) ----------------
__global__ __launch_bounds__(256) void fc1_ln_kernel(
    const float* __restrict__ in,
    const float* __restrict__ g, const float* __restrict__ bb,
    const float* __restrict__ w1, const float* __restrict__ b1,
    const float* __restrict__ lg, const float* __restrict__ lb,
    float* __restrict__ out)
{
    __shared__ __align__(16) short As[64*128];
    __shared__ __align__(16) short BUF[64*128];
    __shared__ float gs[128], bs[128];
    __shared__ float bs1[512], lgs[512], lbs[512];
    int tid = threadIdx.x;
    int n0 = blockIdx.x * 64;
    int srow = tid >> 2, scc = tid & 3;

    if (tid < 128) gs[tid] = g ? g[tid] : 1.f;
    else bs[tid - 128] = bb ? bb[tid - 128] : 0.f;
    for (int idx = tid; idx < 512; idx += 256) {
        bs1[idx] = b1[idx];
        lgs[idx] = lg ? lg[idx] : 1.f;
        lbs[idx] = lb ? lb[idx] : 0.f;
    }

    {   // A: LN staging (one-pass stats across 4 lanes/row)
        const float* ap = in + (size_t)(n0 + srow)*128 + scc*32;
        float vals[32];
        float s = 0.f, sq = 0.f;
        #pragma unroll
        for (int q8 = 0; q8 < 8; ++q8) {
            float4 t4 = *(const float4*)(ap + q8*4);
            vals[q8*4+0]=t4.x; vals[q8*4+1]=t4.y; vals[q8*4+2]=t4.z; vals[q8*4+3]=t4.w;
            s += t4.x + t4.y + t4.z + t4.w;
            sq += t4.x*t4.x + t4.y*t4.y + t4.z*t4.z + t4.w*t4.w;
        }
        s  += __shfl_xor(s, 1);  s  += __shfl_xor(s, 2);
        sq += __shfl_xor(sq, 1); sq += __shfl_xor(sq, 2);
        float mean = s * (1.f/128.f);
        float var = sq * (1.f/128.f) - mean*mean;
        float rs = rsqrtf(fmaxf(var, 0.f) + EPSF);
        __syncthreads();   // gs/bs visible
        #pragma unroll
        for (int c = 0; c < 4; ++c) {
            short8v sv;
            #pragma unroll
            for (int e = 0; e < 8; ++e) {
                int k = scc*32 + c*8 + e;
                sv[e] = f2b((vals[c*8+e] - mean) * rs * gs[k] + bs[k]);
            }
            int cc = scc*4 + c;
            *(short8v*)&As[srow*128 + ((cc ^ (srow & 7)) << 3)] = sv;
        }
    }
    __syncthreads();

    int lane = tid & 63, w4 = tid >> 6;
    int l15 = lane & 15, kgrp = lane >> 4;
    int arow = (w4 << 4) + l15;
    short8v aF[4];
    #pragma unroll
    for (int ks = 0; ks < 4; ++ks) {
        int ch = ks*4 + kgrp;
        aF[ks] = *(short8v*)&As[arow*128 + ((ch ^ (arow & 7)) << 3)];
    }
    float4v acc[32];
    #pragma unroll
    for (int n = 0; n < 32; ++n) acc[n] = (float4v){0.f,0.f,0.f,0.f};

    #pragma unroll
    for (int c8 = 0; c8 < 8; ++c8) {
        __syncthreads();
        {
            const float* bp = w1 + (size_t)(c8*64 + srow)*128 + scc*32;
            #pragma unroll
            for (int c = 0; c < 4; ++c) {
                float4 t0 = *(const float4*)(bp + c*8);
                float4 t1 = *(const float4*)(bp + c*8 + 4);
                short8v sv;
                sv[0]=f2b(t0.x); sv[1]=f2b(t0.y); sv[2]=f2b(t0.z); sv[3]=f2b(t0.w);
                sv[4]=f2b(t1.x); sv[5]=f2b(t1.y); sv[6]=f2b(t1.z); sv[7]=f2b(t1.w);
                int cc = scc*4 + c;
                *(short8v*)&BUF[srow*128 + ((cc ^ (srow & 7)) << 3)] = sv;
            }
        }
        __syncthreads();
        #pragma unroll
        for (int ks = 0; ks < 4; ++ks) {
            int ch = ks*4 + kgrp;
            #pragma unroll
            for (int n = 0; n < 4; ++n) {
                int brow = n*16 + l15;
                short8v bv = *(short8v*)&BUF[brow*128 + ((ch ^ (brow & 7)) << 3)];
                acc[c8*4+n] = __builtin_amdgcn_mfma_f32_16x16x32_bf16(aF[ks], bv, acc[c8*4+n], 0, 0, 0);
            }
        }
    }

    #pragma unroll
    for (int nf = 0; nf < 32; ++nf) {
        int col = nf*16 + l15;
        #pragma unroll
        for (int r = 0; r < 4; ++r)
            acc[nf][r] = gelu_f(acc[nf][r] + bs1[col]);
    }
    float mean[4], rsv[4];
    #pragma unroll
    for (int r = 0; r < 4; ++r) {
        float s = 0.f, sq = 0.f;
        #pragma unroll
        for (int nf = 0; nf < 32; ++nf) { float v = acc[nf][r]; s += v; sq += v*v; }
        s  += __shfl_xor(s, 1);  s  += __shfl_xor(s, 2);  s  += __shfl_xor(s, 4);  s  += __shfl_xor(s, 8);
        sq += __shfl_xor(sq, 1); sq += __shfl_xor(sq, 2); sq += __shfl_xor(sq, 4); sq += __shfl_xor(sq, 8);
        mean[r] = s * (1.f/512.f);
        float var = sq * (1.f/512.f) - mean[r]*mean[r];
        rsv[r] = rsqrtf(fmaxf(var, 0.f) + EPSF);
    }
    #pragma unroll
    for (int r = 0; r < 4; ++r) {
        size_t rowg = (size_t)(n0 + (w4 << 4) + (kgrp << 2) + r);
        #pragma unroll
        for (int nf = 0; nf < 32; ++nf) {
            int col = nf*16 + l15;
            out[rowg*512 + col] = (acc[nf][r] - mean[r]) * rsv[r] * lgs[col] + lbs[col];
        }
    }
}

// ---------------- interaction bias: dual-MFMA (proven r6) ----------------
__global__ __launch_bounds__(256) void bias_kernel(
    const float* __restrict__ p4, const float* __restrict__ prep,
    const float* __restrict__ w0, const float* __restrict__ b0,
    const float* __restrict__ w1, const float* __restrict__ b1,
    const float* __restrict__ w2, const float* __restrict__ b2,
    __hip_bfloat16* __restrict__ bias)
{
    __shared__ float pj[128][8];
    __shared__ float w0s[256], b0s[64], b1s[64], b2s[8];
    __shared__ __align__(16) short U[256*64];
    __shared__ __align__(16) short W1s[64*64];
    __shared__ __align__(16) short W2s[16*64];
    __shared__ short si[256], sj[256];
    int tid = threadIdx.x;
    int b  = blockIdx.x / 33;
    int p  = (blockIdx.x % 33) * 256 + tid;

    w0s[tid] = w0[tid];
    if (tid < 64) { b0s[tid] = b0[tid]; b1s[tid] = b1[tid]; }
    if (tid < 8)  b2s[tid] = b2[tid];
    {
        int o = tid >> 2;
        const float* wp = w1 + o*64 + (tid & 3) * 16;
        #pragma unroll
        for (int h2 = 0; h2 < 2; ++h2) {
            float4 t0 = *(const float4*)(wp + h2*8);
            float4 t1 = *(const float4*)(wp + h2*8 + 4);
            short8v sv;
            sv[0]=f2b(t0.x); sv[1]=f2b(t0.y); sv[2]=f2b(t0.z); sv[3]=f2b(t0.w);
            sv[4]=f2b(t1.x); sv[5]=f2b(t1.y); sv[6]=f2b(t1.z); sv[7]=f2b(t1.w);
            int cc = (tid & 3)*2 + h2;
            *(short8v*)&W1s[o*64 + ((cc ^ (o & 7)) << 3)] = sv;
        }
    }
    if (tid < 128) {
        int o2 = tid >> 3, c = tid & 7;
        short8v sv;
        #pragma unroll
        for (int e = 0; e < 8; ++e)
            sv[e] = (o2 < 8) ? f2b(w2[o2*64 + c*8 + e]) : (short)0;
        *(short8v*)&W2s[o2*64 + ((c ^ (o2 & 7)) << 3)] = sv;
    }
    if (tid < 128) {
        int s = tid;
        const float* pr = prep + ((size_t)b*S_ + s)*3;
        pj[s][0] = pr[0]; pj[s][1] = pr[1]; pj[s][2] = pr[2];
        const float* pp = p4 + ((size_t)b*S_ + s)*4;
        pj[s][3] = pp[0]; pj[s][4] = pp[1]; pj[s][5] = pp[2]; pj[s][6] = pp[3];
    }

    bool valid = p < 8256;
    int i = 0, j = 0;
    if (valid) {
        i = (int)((257.0f - sqrtf((float)(66049 - 8*p))) * 0.5f);
        if (i > 127) i = 127;
        if (i < 0) i = 0;
        while (i > 0 && i*(257 - i)/2 > p) --i;
        while ((i + 1)*(257 - (i + 1))/2 <= p) ++i;
        j = i + (p - i*(257 - i)/2);
    }
    si[tid] = (short)(valid ? i : -1);
    sj[tid] = (short)j;
    __syncthreads();

    float pti = pj[i][0], rapi = pj[i][1], phii = pj[i][2];
    float pxi = pj[i][3], pyi = pj[i][4], pzi = pj[i][5], ei = pj[i][6];
    float ptj = pj[j][0], rapj = pj[j][1], phij = pj[j][2];
    float pxj = pj[j][3], pyj = pj[j][4], pzj = pj[j][5], ej = pj[j][6];

    float dph = phij - phii + PI_F;
    dph = dph - floorf(dph * INV_TWO_PI_F) * TWO_PI_F;
    dph -= PI_F;
    float drap = rapi - rapj;
    float delta = fmaxf(sqrtf(drap*drap + dph*dph), 1e-8f);
    float ptmin = fminf(pti, ptj);
    float kt = fmaxf(ptmin * delta, 1e-8f);
    float z  = fmaxf(ptmin / fmaxf(pti + ptj, 1e-8f), 1e-8f);
    float es = ei + ej, pxs = pxi + pxj, pys = pyi + pyj, pzs = pzi + pzj;
    float m2 = fmaxf(es*es - pxs*pxs - pys*pys - pzs*pzs, 1e-8f);

    float f0 = logf(delta) * BN_SCALE_F;
    float f1 = logf(kt)    * BN_SCALE_F;
    float f2 = logf(z)     * BN_SCALE_F;
    float f3 = logf(m2)    * BN_SCALE_F;

    #pragma unroll
    for (int c8 = 0; c8 < 8; ++c8) {
        short8v sv;
        #pragma unroll
        for (int e = 0; e < 8; ++e) {
            int o = c8*8 + e;
            float a = b0s[o] + w0s[o*4+0]*f0 + w0s[o*4+1]*f1 + w0s[o*4+2]*f2 + w0s[o*4+3]*f3;
            sv[e] = f2b(gelu_fast(a * BN_SCALE_F));
        }
        *(short8v*)&U[tid*64 + ((c8 ^ (tid & 7)) << 3)] = sv;
    }
    __syncthreads();

    int lane = tid & 63, w4 = tid >> 6;
    int l15 = lane & 15, kgrp = lane >> 4;
    float4v acc[4][4];
    #pragma unroll
    for (int m = 0; m < 4; ++m)
        #pragma unroll
        for (int n = 0; n < 4; ++n) acc[m][n] = (float4v){0.f,0.f,0.f,0.f};
    #pragma unroll
    for (int ks = 0; ks < 2; ++ks) {
        int ch = ks*4 + kgrp;
        #pragma unroll
        for (int m = 0; m < 4; ++m) {
            int arow = w4*64 + m*16 + l15;
            short8v av = *(short8v*)&U[arow*64 + ((ch ^ (arow & 7)) << 3)];
            #pragma unroll
            for (int n = 0; n < 4; ++n) {
                int brow = n*16 + l15;
                short8v bv = *(short8v*)&W1s[brow*64 + ((ch ^ (brow & 7)) << 3)];
                acc[m][n] = __builtin_amdgcn_mfma_f32_16x16x32_bf16(av, bv, acc[m][n], 0, 0, 0);
            }
        }
    }

    #pragma unroll
    for (int m = 0; m < 4; ++m) {
        #pragma unroll
        for (int n = 0; n < 4; ++n) {
            int o = n*16 + l15;
            #pragma unroll
            for (int r = 0; r < 4; ++r) {
                int row = w4*64 + m*16 + kgrp*4 + r;
                float u2 = gelu_fast((acc[m][n][r] + b1s[o]) * BN_SCALE_F);
                U[row*64 + (((o >> 3) ^ (row & 7)) << 3) + (o & 7)] = f2b(u2);
            }
        }
    }

    float4v acc2[4];
    #pragma unroll
    for (int m = 0; m < 4; ++m) acc2[m] = (float4v){0.f,0.f,0.f,0.f};
    #pragma unroll
    for (int ks = 0; ks < 2; ++ks) {
        int ch = ks*4 + kgrp;
        short8v bv = *(short8v*)&W2s[l15*64 + ((ch ^ (l15 & 7)) << 3)];
        #pragma unroll
        for (int m = 0; m < 4; ++m) {
            int arow = w4*64 + m*16 + l15;
            short8v av = *(short8v*)&U[arow*64 + ((ch ^ (arow & 7)) << 3)];
            acc2[m] = __builtin_amdgcn_mfma_f32_16x16x32_bf16(av, bv, acc2[m], 0, 0, 0);
        }
    }

    size_t base = ((size_t)b*H_)*S_*S_;
    #pragma unroll
    for (int m = 0; m < 4; ++m) {
        #pragma unroll
        for (int r = 0; r < 4; ++r) {
            int row = w4*64 + m*16 + kgrp*4 + r;
            int ii = si[row], jj = sj[row];
            if (l15 < 8 && ii >= 0) {
                float v = gelu_fast((acc2[m][r] + b2s[l15]) * BN_SCALE_F);
                __hip_bfloat16 bv16 = __float2bfloat16(v);
                bias[base + (size_t)l15*S_*S_ + (size_t)ii*S_ + jj] = bv16;
                bias[base + (size_t)l15*S_*S_ + (size_t)jj*S_ + ii] = bv16;
            }
        }
    }
}

// ---------------- generic LayerNorm (64 threads/row) ----------------
template<int W>
__global__ __launch_bounds__(64) void ln_kernel(
    const float* __restrict__ in, float* __restrict__ out,
    const float* __restrict__ g, const float* __restrict__ bb,
    const float* __restrict__ res)
{
    constexpr int E = W / 64;
    int row = blockIdx.x;
    int lane = threadIdx.x;
    const float* r = in + (size_t)row * W;
    float vals[E];
    float s = 0.f;
    #pragma unroll
    for (int e = 0; e < E; ++e) { vals[e] = r[lane + 64*e]; s += vals[e]; }
    #pragma unroll
    for (int o = 32; o > 0; o >>= 1) s += __shfl_xor(s, o);
    float m = s * (1.f / W);
    float vsum = 0.f;
    #pragma unroll
    for (int e = 0; e < E; ++e) { float d = vals[e] - m; vsum += d*d; }
    #pragma unroll
    for (int o = 32; o > 0; o >>= 1) vsum += __shfl_xor(vsum, o);
    float rs = rsqrtf(vsum * (1.f / W) + EPSF);
    #pragma unroll
    for (int e = 0; e < E; ++e) {
        int c = lane + 64*e;
        float v = (vals[e] - m) * rs;
        if (g) v = v * g[c] + bb[c];
        if (res) v += res[(size_t)row*W + c];
        out[(size_t)row*W + c] = v;
    }
}

// ---------------- MFMA particle attention per (b,h) (proven r8) ----------------
__global__ __launch_bounds__(256) void attn_kernel(
    const float* __restrict__ q, const float* __restrict__ k, const float* __restrict__ v,
    const __hip_bfloat16* __restrict__ bias, const float* __restrict__ kpm,
    const float* __restrict__ gam, int layer, float* __restrict__ out)
{
    int bh = blockIdx.x;
    int b = bh >> 3, h = bh & 7;
    __shared__ __align__(16) short qs[128][40];
    __shared__ __align__(16) short ks[128][40];
    __shared__ __align__(16) short vst[16][136];
    __shared__ __align__(16) short pb[64][136];
    int tid = threadIdx.x;

    {
        int r = tid >> 1, hh = tid & 1;
        const float* qp = q + ((size_t)(b*S_ + r))*D_ + h*16 + hh*8;
        const float* kp = k + ((size_t)(b*S_ + r))*D_ + h*16 + hh*8;
        float4 a0 = *(const float4*)qp;
        float4 a1 = *(const float4*)(qp + 4);
        float4 c0 = *(const float4*)kp;
        float4 c1 = *(const float4*)(kp + 4);
        short8v sq, sk, zz;
        sq[0]=f2b(a0.x); sq[1]=f2b(a0.y); sq[2]=f2b(a0.z); sq[3]=f2b(a0.w);
        sq[4]=f2b(a1.x); sq[5]=f2b(a1.y); sq[6]=f2b(a1.z); sq[7]=f2b(a1.w);
        sk[0]=f2b(c0.x); sk[1]=f2b(c0.y); sk[2]=f2b(c0.z); sk[3]=f2b(c0.w);
        sk[4]=f2b(c1.x); sk[5]=f2b(c1.y); sk[6]=f2b(c1.z); sk[7]=f2b(c1.w);
        #pragma unroll
        for (int e = 0; e < 8; ++e) zz[e] = 0;
        *(short8v*)&qs[r][hh*8] = sq;
        *(short8v*)&ks[r][hh*8] = sk;
        *(short8v*)&qs[r][16 + hh*8] = zz;
        *(short8v*)&ks[r][16 + hh*8] = zz;
    }
    {
        int j = tid >> 1, dg = (tid & 1)*8;
        const float* vp = v + ((size_t)(b*S_ + j))*D_ + h*16 + dg;
        float4 v0 = *(const float4*)vp;
        float4 v1 = *(const float4*)(vp + 4);
        vst[dg+0][j] = f2b(v0.x); vst[dg+1][j] = f2b(v0.y);
        vst[dg+2][j] = f2b(v0.z); vst[dg+3][j] = f2b(v0.w);
        vst[dg+4][j] = f2b(v1.x); vst[dg+5][j] = f2b(v1.y);
        vst[dg+6][j] = f2b(v1.z); vst[dg+7][j] = f2b(v1.w);
    }
    float gm = gam[layer*H_ + h];
    __syncthreads();

    int lane = tid & 63, w = tid >> 6;
    int l15 = lane & 15, l4 = lane >> 4;

    float msk[8];
    #pragma unroll
    for (int n = 0; n < 8; ++n) msk[n] = kpm[b*S_ + n*16 + l15];

    #pragma unroll
    for (int half = 0; half < 2; ++half) {
        int mrow = half*64 + w*16;
        short8v aq = *(short8v*)&qs[mrow + l15][l4*8];
        float4v sf[8];
        #pragma unroll
        for (int n = 0; n < 8; ++n) {
            short8v bk = *(short8v*)&ks[n*16 + l15][l4*8];
            sf[n] = __builtin_amdgcn_mfma_f32_16x16x32_bf16(aq, bk, (float4v){0.f,0.f,0.f,0.f}, 0, 0, 0);
        }
        #pragma unroll
        for (int r = 0; r < 4; ++r) {
            int srow = mrow + l4*4 + r;
            const __hip_bfloat16* bp = bias + ((size_t)(b*H_ + h)*S_ + srow)*S_ + l15;
            float sc[8];
            float mx = -1e30f;
            #pragma unroll
            for (int n = 0; n < 8; ++n) {
                float s = sf[n][r]*0.25f + __bfloat162float(bp[n*16]);
                if (msk[n] != 0.f) s = -1e30f;
                sc[n] = s;
                mx = fmaxf(mx, s);
            }
            mx = fmaxf(mx, __shfl_xor(mx, 1));
            mx = fmaxf(mx, __shfl_xor(mx, 2));
            mx = fmaxf(mx, __shfl_xor(mx, 4));
            mx = fmaxf(mx, __shfl_xor(mx, 8));
            float sum = 0.f;
            #pragma unroll
            for (int n = 0; n < 8; ++n) { float e = __expf(sc[n] - mx); sc[n] = e; sum += e; }
            sum += __shfl_xor(sum, 1);
            sum += __shfl_xor(sum, 2);
            sum += __shfl_xor(sum, 4);
            sum += __shfl_xor(sum, 8);
            float inv = 1.f / sum;
            int lrow = w*16 + l4*4 + r;
            #pragma unroll
            for (int n = 0; n < 8; ++n)
                pb[lrow][n*16 + l15] = f2b(sc[n] * inv);
        }
        float4v of = (float4v){0.f,0.f,0.f,0.f};
        #pragma unroll
        for (int ks4 = 0; ks4 < 4; ++ks4) {
            short8v pa = *(short8v*)&pb[w*16 + l15][ks4*32 + l4*8];
            short8v vb = *(short8v*)&vst[l15][ks4*32 + l4*8];
            of = __builtin_amdgcn_mfma_f32_16x16x32_bf16(pa, vb, of, 0, 0, 0);
        }
        #pragma unroll
        for (int r = 0; r < 4; ++r)
            out[((size_t)(b*S_ + mrow + l4*4 + r))*D_ + h*16 + l15] = of[r] * gm;
    }
}

// ---------------- class-token attention ----------------
__global__ __launch_bounds__(256) void cattn_kernel(
    const float* __restrict__ qc, const float* __restrict__ kc, const float* __restrict__ vc,
    const float* __restrict__ kpm, const float* __restrict__ gam,
    int layer, float* __restrict__ outc)
{
    int b = blockIdx.x / H_, h = blockIdx.x % H_;
    __shared__ float sc[132];
    int tid = threadIdx.x;
    const int T = S_ + 1;
    if (tid < T) {
        float acc = 0.f;
        #pragma unroll
        for (int d = 0; d < 16; ++d)
            acc += qc[(size_t)b*D_ + h*16 + d] * kc[((size_t)b*T + tid)*D_ + h*16 + d];
        acc *= 0.25f;
        if (tid > 0 && kpm[b*S_ + tid - 1] != 0.f) acc = -1e30f;
        sc[tid] = acc;
    }
    __syncthreads();
    if (tid == 0) {
        float m = -1e30f;
        for (int jj = 0; jj < T; ++jj) m = fmaxf(m, sc[jj]);
        float sum = 0.f;
        for (int jj = 0; jj < T; ++jj) { float e = __expf(sc[jj] - m); sc[jj] = e; sum += e; }
        float inv = 1.f / sum;
        for (int jj = 0; jj < T; ++jj) sc[jj] *= inv;
    }
    __syncthreads();
    if (tid < 16) {
        float acc = 0.f;
        for (int jj = 0; jj < T; ++jj) acc += sc[jj] * vc[((size_t)b*T + jj)*D_ + h*16 + tid];
        outc[(size_t)b*D_ + h*16 + tid] = acc * gam[layer*H_ + h];
    }
}

// ---------------- small helpers ----------------
__global__ __launch_bounds__(256) void bcast_ct_kernel(const float* __restrict__ ct, float* __restrict__ xc)
{
    int idx = blockIdx.x * 256 + threadIdx.x;
    xc[idx] = ct[idx & (D_ - 1)];
}

__global__ __launch_bounds__(256) void concat_kernel(
    const float* __restrict__ xc, const float* __restrict__ xp, float* __restrict__ xx)
{
    int idx = blockIdx.x * 256 + threadIdx.x;
    int d = idx & (D_ - 1);
    int r = idx >> 7;
    int b = r / (S_ + 1);
    int s = r % (S_ + 1);
    xx[idx] = (s == 0) ? xc[(size_t)b*D_ + d] : xp[((size_t)b*S_ + (s - 1))*D_ + d];
}

// ---------------- final head ----------------
__global__ __launch_bounds__(128) void head_kernel(
    const float* __restrict__ u, const float* __restrict__ fc_w, const float* __restrict__ fc_b,
    const float* __restrict__ fin_w, const float* __restrict__ fin_b, float* __restrict__ out)
{
    __shared__ float us[128], r0[128], r1[128];
    int b = blockIdx.x, tid = threadIdx.x;
    us[tid] = u[(size_t)b*D_ + tid];
    __syncthreads();
    float acc = fc_b[tid];
    for (int kk = 0; kk < 128; ++kk) acc += fc_w[tid*128 + kk] * us[kk];
    float rl = fmaxf(acc, 0.f);
    r0[tid] = fin_w[tid] * rl;
    r1[tid] = fin_w[128 + tid] * rl;
    __syncthreads();
    #pragma unroll
    for (int o = 64; o > 0; o >>= 1) {
        if (tid < o) { r0[tid] += r0[tid + o]; r1[tid] += r1[tid + o]; }
        __syncthreads();
    }
    if (tid == 0) {
        float l0 = r0[0] + fin_b[0], l1 = r1[0] + fin_b[1];
        float m = fmaxf(l0, l1);
        float e0 = __expf(l0 - m), e1 = __expf(l1 - m);
        float inv = 1.f / (e0 + e1);
        out[b*2 + 0] = e0 * inv;
        out[b*2 + 1] = e1 * inv;
    }
}

// ---------------- orchestration ----------------
extern "C" void kernel_launch(void* const* d_in, const int* in_sizes, int n_in,
                              void* d_out, int out_size, void* d_ws, size_t ws_size,
                              hipStream_t stream)
{
    (void)in_sizes; (void)n_in; (void)out_size;
    const float* x     = (const float*)d_in[0];
    const float* p4    = (const float*)d_in[1];
    const float* pe_w0 = (const float*)d_in[2];
    const float* pe_b0 = (const float*)d_in[3];
    const float* pe_w1 = (const float*)d_in[4];
    const float* pe_b1 = (const float*)d_in[5];
    const float* pe_w2 = (const float*)d_in[6];
    const float* pe_b2 = (const float*)d_in[7];
    const float* ie_w0 = (const float*)d_in[8];
    const float* ie_b0 = (const float*)d_in[9];
    const float* ie_w1 = (const float*)d_in[10];
    const float* ie_b1 = (const float*)d_in[11];
    const float* ie_w2 = (const float*)d_in[12];
    const float* ie_b2 = (const float*)d_in[13];
    const float* wq    = (const float*)d_in[14];
    const float* wk    = (const float*)d_in[15];
    const float* wv    = (const float*)d_in[16];
    const float* wo    = (const float*)d_in[17];
    const float* gam   = (const float*)d_in[18];
    const float* ln_g  = (const float*)d_in[19];
    const float* ln_b  = (const float*)d_in[20];
    const float* lnfc_g= (const float*)d_in[21];
    const float* lnfc_b= (const float*)d_in[22];
    const float* fc1_w = (const float*)d_in[23];
    const float* fc1_b = (const float*)d_in[24];
    const float* fc2_w = (const float*)d_in[25];
    const float* fc2_b = (const float*)d_in[26];
    const float* lam   = (const float*)d_in[27];
    const float* ct    = (const float*)d_in[28];
    const float* fc_w  = (const float*)d_in[29];
    const float* fc_b  = (const float*)d_in[30];
    const float* fin_w = (const float*)d_in[31];
    const float* fin_b = (const float*)d_in[32];

    float* ws = (float*)d_ws;
    const size_t o_bias = 0;
    const size_t o_prep = o_bias + 8388608;
    const size_t o_kpm  = o_prep + 49152;
    const size_t o_xp   = o_kpm  + 16384;
    const size_t o_b1   = o_xp   + 2097152;
    const size_t o_b2   = o_b1   + 2097152;
    const size_t o_b3   = o_b2   + 8388608;
    const size_t o_xx   = o_b3   + 2097152;
    const size_t o_xc   = o_xx   + 2113536;
    const size_t o_t1   = o_xc   + 16384;
    const size_t o_t2   = o_t1   + 16384;
    const size_t o_ac   = o_t2   + 65536;
    const size_t o_u    = o_ac   + 16384;
    const size_t o_end  = o_u    + 16384;

    size_t used_bytes = o_end * sizeof(float);
    if (used_bytes > ws_size) used_bytes = ws_size;
    hipMemsetAsync(d_ws, 0, used_bytes, stream);

    __hip_bfloat16* biasb = (__hip_bfloat16*)(ws + o_bias);
    float* prep = ws + o_prep;
    float* kpm  = ws + o_kpm;
    float* xp   = ws + o_xp;
    float* b1   = ws + o_b1;
    float* b2   = ws + o_b2;
    float* b3   = ws + o_b3;
    float* xx   = ws + o_xx;
    float* xc   = ws + o_xc;
    float* t2   = ws + o_t2;
    float* ac   = ws + o_ac;
    float* ufin = ws + o_u;

    const int NT = B_ * S_;        // 16384
    const int NC = B_ * (S_ + 1);  // 16512

    prep_kernel<<<NT/256, 256, 0, stream>>>(x, p4, prep, kpm);
    embed1_kernel<<<NT/2, 256, 0, stream>>>(x, pe_w0, pe_b0, b1);
    fc1_ln_kernel<<<NT/64, 256, 0, stream>>>(b1, nullptr, nullptr, pe_w1, pe_b1, nullptr, nullptr, b2);
    linmm_kernel<1,false><<<dim3(NT/64, 2), 256, 0, stream>>>(b2, pe_w2, pe_b2, xp, nullptr, nullptr, NT, 512, 128);
    bias_kernel<<<B_*33, 256, 0, stream>>>(p4, prep, ie_w0, ie_b0, ie_w1, ie_b1, ie_w2, ie_b2, biasb);

    float* qb = b2;
    float* kb = b2 + 2097152;
    float* vb = b2 + 4194304;

    // ---- particle blocks ----
    for (int i = 0; i < 8; ++i) {
        const float* g0p = ln_g + (size_t)(i*3 + 0)*D_; const float* b0p = ln_b + (size_t)(i*3 + 0)*D_;
        const float* g1p = ln_g + (size_t)(i*3 + 1)*D_; const float* b1p = ln_b + (size_t)(i*3 + 1)*D_;
        const float* g2p = ln_g + (size_t)(i*3 + 2)*D_; const float* b2p = ln_b + (size_t)(i*3 + 2)*D_;

        ln_kernel<128><<<NT, 64, 0, stream>>>(xp, b1, g0p, b0p, nullptr);
        qkv3_kernel<<<dim3(NT/64, 2, 3), 256, 0, stream>>>(
            b1, wq + (size_t)i*D_*D_, wk + (size_t)i*D_*D_, wv + (size_t)i*D_*D_, qb, kb, vb);
        attn_kernel<<<B_*H_, 256, 0, stream>>>(qb, kb, vb, biasb, kpm, gam, i, b1);
        wo_ln_kernel<<<NT/64, 256, 0, stream>>>(b1, wo + (size_t)i*D_*D_, g1p, b1p, xp, xp);
        fc1_ln_kernel<<<NT/64, 256, 0, stream>>>(xp, g2p, b2p,
            fc1_w + (size_t)i*F_*D_, fc1_b + (size_t)i*F_,
            lnfc_g + (size_t)i*F_, lnfc_b + (size_t)i*F_, b2);
        linmm_kernel<0,true><<<dim3(NT/64, 2), 256, 0, stream>>>(b2, fc2_w + (size_t)i*D_*F_, fc2_b + (size_t)i*D_, xp, xp, lam + (size_t)i*D_, NT, F_, D_);
    }

    // ---- class blocks ----
    bcast_ct_kernel<<<B_*D_/256, 256, 0, stream>>>(ct, xc);
    float* kc = b2;
    float* vc = b2 + 2113536;
    for (int i = 8; i < 10; ++i) {
        const float* g0p = ln_g + (size_t)(i*3 + 0)*D_; const float* b0p = ln_b + (size_t)(i*3 + 0)*D_;
        const float* g1p = ln_g + (size_t)(i*3 + 1)*D_; const float* b1p = ln_b + (size_t)(i*3 + 1)*D_;
        const float* g2p = ln_g + (size_t)(i*3 + 2)*D_; const float* b2p = ln_b + (size_t)(i*3 + 2)*D_;

        concat_kernel<<<(B_*(S_+1)*D_)/256, 256, 0, stream>>>(xc, xp, xx);
        ln_kernel<128><<<NC, 64, 0, stream>>>(xx, xx, g0p, b0p, nullptr);
        linmm_kernel<0,false><<<dim3(NC/64, 2), 256, 0, stream>>>(xx, wk + (size_t)i*D_*D_, nullptr, kc, nullptr, nullptr, NC, D_, D_);
        linmm_kernel<0,false><<<dim3(NC/64, 2), 256, 0, stream>>>(xx, wv + (size_t)i*D_*D_, nullptr, vc, nullptr, nullptr, NC, D_, D_);
        linmm_kernel<0,false><<<dim3(B_/64, 2), 256, 0, stream>>>(xc, wq + (size_t)i*D_*D_, nullptr, b3, nullptr, nullptr, B_, D_, D_);
        cattn_kernel<<<B_*H_, 256, 0, stream>>>(b3, kc, vc, kpm, gam, i, ac);
        linmm_kernel<0,false><<<dim3(B_/64, 2), 256, 0, stream>>>(ac, wo + (size_t)i*D_*D_, nullptr, b3, nullptr, nullptr, B_, D_, D_);
        ln_kernel<128><<<B_, 64, 0, stream>>>(b3, xc, g1p, b1p, xc);
        fc1_ln_kernel<<<B_/64, 256, 0, stream>>>(xc, g2p, b2p,
            fc1_w + (size_t)i*F_*D_, fc1_b + (size_t)i*F_,
            lnfc_g + (size_t)i*F_, lnfc_b + (size_t)i*F_, t2);
        linmm_kernel<0,true><<<dim3(B_/64, 2), 256, 0, stream>>>(t2, fc2_w + (size_t)i*D_*F_, fc2_b + (size_t)i*D_, xc, xc, lam + (size_t)i*D_, B_, F_, D_);
    }

    // ---- head ----
    ln_kernel<128><<<B_, 64, 0, stream>>>(xc, ufin, nullptr, nullptr, nullptr);
    head_kernel<<<B_, 128, 0, stream>>>(ufin, fc_w, fc_b, fin_w, fin_b, (float*)d_out);
}